// Round 6
// baseline (432.620 us; speedup 1.0000x reference)
//
#include <hip/hip_runtime.h>

// ---------------------------------------------------------------------------
// GIN inference, round 16:
//  - Gather latency-chain halved: each row now owned by 32 lanes (2 edge
//    halves x 16 chunk-lanes). Per half ~deg/2 edges -> ONE 8-deep latency
//    round instead of two. Halves combined with __shfl_xor(acc,16) in-wave
//    (no LDS, no sync — this is what round 13's LDS/pass combine got wrong).
//  - Block = 512 threads / 16 rows, grid 3125, 8 waves own 1 nt-tile each in
//    the GEMM phases. __launch_bounds__(512,8) keeps VGPR<=64 -> 32 waves/CU.
//  - colL staging dropped (round 15: neutral). Layer1 back to round-14 form.
//  - Rest unchanged: fused agg+GEMM1+GEMM2+(writeout|pool), permuted column
//    layout (position p <-> column (p&7)*16 + (p>>3)), pool-from-LDS on last.
// ---------------------------------------------------------------------------

typedef __attribute__((ext_vector_type(8))) short short8;   // 8 bf16 (4 VGPRs)
typedef __attribute__((ext_vector_type(4))) float floatx4;  // 4 fp32 acc

__device__ __forceinline__ unsigned f2bf(float f) {
    unsigned u = __float_as_uint(f);
    return (u + 0x7fffu + ((u >> 16) & 1u)) >> 16;   // RNE
}
__device__ __forceinline__ float bf2f(unsigned short b) {
    return __uint_as_float(((unsigned)b) << 16);
}
__device__ __forceinline__ float bflo(unsigned u) { return __uint_as_float(u << 16); }
__device__ __forceinline__ float bfhi(unsigned u) { return __uint_as_float(u & 0xffff0000u); }

__device__ __forceinline__ uint4 pack8bf(const float* v) {
    uint4 o;
    o.x = f2bf(v[0]) | (f2bf(v[1]) << 16);
    o.y = f2bf(v[2]) | (f2bf(v[3]) << 16);
    o.z = f2bf(v[4]) | (f2bf(v[5]) << 16);
    o.w = f2bf(v[6]) | (f2bf(v[7]) << 16);
    return o;
}

// ======================= bucketed CSR build =======================

__global__ void bucket_hist(const int* __restrict__ dstA, int* __restrict__ bcnt,
                            int E, int nb) {
    __shared__ int hist[512];
    int tid = threadIdx.x;
    int start = blockIdx.x * 4096;
    for (int i = tid; i < 512; i += 256) hist[i] = 0;
    __syncthreads();
#pragma unroll
    for (int t = 0; t < 16; ++t) {
        int e = start + t * 256 + tid;
        if (e < E) atomicAdd(&hist[dstA[e] >> 7], 1);
    }
    __syncthreads();
    for (int i = tid; i < nb; i += 256)
        if (hist[i]) atomicAdd(&bcnt[i], hist[i]);
}

__global__ void scan_buckets(const int* __restrict__ bcnt, int* __restrict__ boff,
                             int* __restrict__ bcur, int* __restrict__ rowptr,
                             int nb, int N) {
    __shared__ int sa[512], sb[512];
    int t = threadIdx.x;
    sa[t] = (t < nb) ? bcnt[t] : 0;
    __syncthreads();
    int* ps = sa;
    int* pd = sb;
    for (int o = 1; o < 512; o <<= 1) {
        pd[t] = ps[t] + ((t >= o) ? ps[t - o] : 0);
        __syncthreads();
        int* tmp = ps; ps = pd; pd = tmp;
    }
    if (t <= nb) boff[t] = (t == 0) ? 0 : ps[t - 1];
    if (t < nb) bcur[t] = (t == 0) ? 0 : ps[t - 1];
    if (t == 0) rowptr[N] = ps[nb - 1];
}

__global__ void bucket_scatter(const int* __restrict__ srcA, const int* __restrict__ dstA,
                               int* __restrict__ bcur, unsigned* __restrict__ staging,
                               int E, int nb) {
    __shared__ int hist[512];
    __shared__ int sa[512], sb[512];
    __shared__ int toff[513];
    __shared__ int gbase[512];
    __shared__ unsigned pk[4096];
    __shared__ unsigned short bkt[4096];
    int tid = threadIdx.x;
    int start = blockIdx.x * 4096;
    for (int i = tid; i < 512; i += 256) hist[i] = 0;
    __syncthreads();
    int bidx[16], rank[16];
    unsigned pval[16];
#pragma unroll
    for (int t = 0; t < 16; ++t) {
        int e = start + t * 256 + tid;
        bidx[t] = -1;
        if (e < E) {
            int d = dstA[e];
            int s = srcA[e];
            int b = d >> 7;
            bidx[t] = b;
            rank[t] = atomicAdd(&hist[b], 1);
            pval[t] = ((unsigned)s << 7) | (unsigned)(d & 127);
        }
    }
    __syncthreads();
    sa[tid] = hist[tid];
    sa[tid + 256] = hist[tid + 256];
    __syncthreads();
    int* ps = sa;
    int* pd = sb;
    for (int o = 1; o < 512; o <<= 1) {
        pd[tid] = ps[tid] + ((tid >= o) ? ps[tid - o] : 0);
        int j2 = tid + 256;
        pd[j2] = ps[j2] + ((j2 >= o) ? ps[j2 - o] : 0);
        __syncthreads();
        int* tmp = ps; ps = pd; pd = tmp;
    }
    toff[tid + 1] = ps[tid];
    toff[tid + 257] = ps[tid + 256];
    if (tid == 0) toff[0] = 0;
    __syncthreads();
    for (int b = tid; b < nb; b += 256) {
        int c = hist[b];
        gbase[b] = c ? atomicAdd(&bcur[b], c) : 0;
    }
#pragma unroll
    for (int t = 0; t < 16; ++t)
        if (bidx[t] >= 0) {
            int pos = toff[bidx[t]] + rank[t];
            pk[pos] = pval[t];
            bkt[pos] = (unsigned short)bidx[t];
        }
    __syncthreads();
    int total = toff[512];
    for (int i = tid; i < total; i += 256) {
        int b = bkt[i];
        staging[gbase[b] + (i - toff[b])] = pk[i];
    }
}

__global__ void bucket_build(const unsigned* __restrict__ staging, const int* __restrict__ boff,
                             int* __restrict__ rowptr, int* __restrict__ col, int N) {
    __shared__ int deg[128], sca[128], scb[128], curL[128];
    __shared__ unsigned pk[4096];
    __shared__ int colL[4096];
    int b = blockIdx.x, tid = threadIdx.x;
    int lo = boff[b], hi = boff[b + 1];
    int cnt = hi - lo;
    if (cnt > 4096) cnt = 4096;
    for (int i = tid; i < cnt; i += 256) pk[i] = staging[lo + i];
    if (tid < 128) deg[tid] = 0;
    __syncthreads();
    for (int i = tid; i < cnt; i += 256) atomicAdd(&deg[pk[i] & 127u], 1);
    __syncthreads();
    if (tid < 128) sca[tid] = deg[tid];
    __syncthreads();
    int* ps = sca;
    int* pd = scb;
    for (int o = 1; o < 128; o <<= 1) {
        if (tid < 128) pd[tid] = ps[tid] + ((tid >= o) ? ps[tid - o] : 0);
        __syncthreads();
        int* tmp = ps; ps = pd; pd = tmp;
    }
    if (tid < 128) {
        int excl = tid ? ps[tid - 1] : 0;
        curL[tid] = excl;
        int node = b * 128 + tid;
        if (node < N) rowptr[node] = lo + excl;
    }
    __syncthreads();
    for (int i = tid; i < cnt; i += 256) {
        unsigned v = pk[i];
        int p = atomicAdd(&curL[v & 127u], 1);
        colL[p] = (int)(v >> 7);
    }
    __syncthreads();
    for (int i = tid; i < cnt; i += 256) col[lo + i] = colL[i];
}

// ======================= weight packing (perm-aware) =======================

__global__ void pack_W_all(const float* __restrict__ c1W2, const float* __restrict__ csW1,
                           const float* __restrict__ csW2, unsigned short* __restrict__ Wp,
                           int NL) {
    int slot = blockIdx.x >> 6;
    int r = (blockIdx.x & 63) * 256 + threadIdx.x;   // 0..16383
    const float* W = (slot == 0) ? c1W2
                   : (slot <= NL ? csW1 + (size_t)(slot - 1) * 16384
                                 : csW2 + (size_t)(slot - 1 - NL) * 16384);
    int j = r & 7, lane = (r >> 3) & 63, nt = (r >> 9) & 7, ks = (r >> 12) & 3;
    int u = ks * 32 + (lane >> 4) * 8 + j;
    int k = (u & 7) * 16 + (u >> 3);                 // pi(u)
    int n = nt * 16 + (lane & 15);
    Wp[(size_t)slot * 16384 + r] = (unsigned short)f2bf(W[k * 128 + n]);
}

// ======================= helpers =======================

__device__ __forceinline__ void addrow(float* acc, uint4 v) {
    acc[0] += bflo(v.x); acc[1] += bfhi(v.x);
    acc[2] += bflo(v.y); acc[3] += bfhi(v.y);
    acc[4] += bflo(v.z); acc[5] += bfhi(v.z);
    acc[6] += bflo(v.w); acc[7] += bfhi(v.w);
}

// ======================= fused GIN layer (agg + MLP + out/pool) ============
// 512 threads / block, 16 rows / block. Phase A: 32 lanes per row (2 edge
// halves x 16 chunk-lanes); halves combined via __shfl_xor(.,16) in-wave.
// Phases B/C: 8 waves, one nt-tile each. Permuted column layout:
// position p <-> actual column (p&7)*16 + (p>>3).

__launch_bounds__(512, 8)
__global__ void gin_fused(const uint4* __restrict__ h4,
                          const int* __restrict__ rowptr, const int* __restrict__ col,
                          const unsigned short* __restrict__ W1p, const float* __restrict__ b1,
                          const unsigned short* __restrict__ W2p, const float* __restrict__ b2,
                          const float* __restrict__ gamma, const float* __restrict__ beta,
                          const float* __restrict__ mean, const float* __restrict__ var,
                          unsigned short* __restrict__ out,
                          const int* __restrict__ batch, float* __restrict__ pooled,
                          int N, int last) {
    __shared__ unsigned short abuf[16][136];   // agg output, reused for BN output
    __shared__ unsigned short hbuf[16][136];   // GEMM1 -> GEMM2 handoff
    int tid = threadIdx.x;
    int row0 = blockIdx.x * 16;
    if (row0 >= N) return;
    int lane = tid & 63;
    int wv = tid >> 6;                         // 0..7

    // ---- phase A: gather; 32 lanes/row = 2 edge-halves x 16 chunks ----
    {
        int slot = tid >> 5;                   // row in block, 0..15
        int hh = (tid >> 4) & 1;               // edge half
        int sl = tid & 15;                     // 16B chunk of the 256B row
        int n = row0 + slot;
        if (n > N - 1) n = N - 1;              // tail: duplicate row N-1 (discarded)
        float acc[8];
        if (hh == 0) {
            uint4 self = h4[(size_t)n * 16 + sl];
            acc[0] = bflo(self.x); acc[1] = bfhi(self.x);
            acc[2] = bflo(self.y); acc[3] = bfhi(self.y);
            acc[4] = bflo(self.z); acc[5] = bfhi(self.z);
            acc[6] = bflo(self.w); acc[7] = bfhi(self.w);
        } else {
#pragma unroll
            for (int t = 0; t < 8; ++t) acc[t] = 0.f;
        }
        int e0 = rowptr[n], e1 = rowptr[n + 1];
        int half = (e1 - e0 + 1) >> 1;
        int ja = hh ? e0 + half : e0;
        int jb = hh ? e1 : e0 + half;
        int j = ja;
        for (; j + 8 <= jb; j += 8) {
            int s[8];
#pragma unroll
            for (int t = 0; t < 8; ++t) s[t] = col[j + t];
            uint4 v[8];
#pragma unroll
            for (int t = 0; t < 8; ++t) v[t] = h4[(size_t)s[t] * 16 + sl];
#pragma unroll
            for (int t = 0; t < 8; ++t) addrow(acc, v[t]);
        }
        for (; j + 4 <= jb; j += 4) {
            int s0 = col[j], s1 = col[j + 1], s2 = col[j + 2], s3 = col[j + 3];
            uint4 v0 = h4[(size_t)s0 * 16 + sl];
            uint4 v1 = h4[(size_t)s1 * 16 + sl];
            uint4 v2 = h4[(size_t)s2 * 16 + sl];
            uint4 v3 = h4[(size_t)s3 * 16 + sl];
            addrow(acc, v0); addrow(acc, v1); addrow(acc, v2); addrow(acc, v3);
        }
        for (; j < jb; ++j) addrow(acc, h4[(size_t)col[j] * 16 + sl]);
        // combine halves in-wave: partner is lane^16 (same wave, same row)
#pragma unroll
        for (int t = 0; t < 8; ++t) acc[t] += __shfl_xor(acc[t], 16);
        if (hh == 0) *(uint4*)&abuf[slot][sl * 8] = pack8bf(acc);
    }
    __syncthreads();

    // ---- phase B: GEMM1 (wave owns nt-tile ntg = wv) ----
    int m = lane & 15, q = lane >> 4;
    short8 a0[4];
#pragma unroll
    for (int ks = 0; ks < 4; ++ks)
        a0[ks] = *(const short8*)&abuf[m][ks * 32 + q * 8];
    floatx4 c0 = (floatx4){0.f, 0.f, 0.f, 0.f};
#pragma unroll
    for (int ks = 0; ks < 4; ++ks) {
        short8 w = *(const short8*)&W1p[(((ks << 3) + wv) * 64 + lane) * 8];
        c0 = __builtin_amdgcn_mfma_f32_16x16x32_bf16(a0[ks], w, c0, 0, 0, 0);
    }
    {
        // column wv*16+m -> permuted position m*8+wv
        float bv0 = b1[wv * 16 + m];
        int pp = m * 8 + wv;
#pragma unroll
        for (int rg = 0; rg < 4; ++rg)
            hbuf[q * 4 + rg][pp] = (unsigned short)f2bf(fmaxf(c0[rg] + bv0, 0.f));
    }
    __syncthreads();

    // ---- phase C: GEMM2 + BN epilogue -> abuf (reuse) ----
    short8 d0[4];
#pragma unroll
    for (int ks = 0; ks < 4; ++ks)
        d0[ks] = *(const short8*)&hbuf[m][ks * 32 + q * 8];
    floatx4 e0v = (floatx4){0.f, 0.f, 0.f, 0.f};
#pragma unroll
    for (int ks = 0; ks < 4; ++ks) {
        short8 w = *(const short8*)&W2p[(((ks << 3) + wv) * 64 + lane) * 8];
        e0v = __builtin_amdgcn_mfma_f32_16x16x32_bf16(d0[ks], w, e0v, 0, 0, 0);
    }
    {
        int cidx = wv * 16 + m;
        float bv = b2[cidx];
        float s = gamma[cidx] * rsqrtf(var[cidx] + 1e-5f);
        float sh = beta[cidx] - mean[cidx] * s;
        int pp = m * 8 + wv;
#pragma unroll
        for (int rg = 0; rg < 4; ++rg)
            abuf[q * 4 + rg][pp] =
                (unsigned short)f2bf(fmaf(fmaxf(e0v[rg] + bv, 0.f), s, sh));
    }
    __syncthreads();

    // ---- phase D: coalesced writeout (non-last) or pool-from-LDS (last) ----
    if (!last) {
        int lr = tid >> 5;
        int cb = (tid & 31) * 4;
        int n = row0 + lr;
        if (n < N) *(uint2*)&out[(size_t)n * 128 + cb] = *(const uint2*)&abuf[lr][cb];
    } else if (tid < 128) {
        int n1 = N - row0; if (n1 > 16) n1 = 16;
        int cg = batch[row0];
        float acc = 0.f;
        for (int lr = 0; lr < n1; ++lr) {
            int g = batch[row0 + lr];
            if (g != cg) {
                atomicAdd(&pooled[(size_t)cg * 128 + tid], acc);
                acc = 0.f;
                cg = g;
            }
            acc += bf2f(abuf[lr][tid]);
        }
        atomicAdd(&pooled[(size_t)cg * 128 + tid], acc);
    }
}

// ======================= fused layer 1 (agg2 + W1-MLP + W2 GEMM) ===========

__launch_bounds__(256)
__global__ void layer1_fused(const float* __restrict__ x,
                             const int* __restrict__ rowptr, const int* __restrict__ col,
                             const float* __restrict__ W1, const float* __restrict__ b1,
                             const unsigned short* __restrict__ W2p, const float* __restrict__ b2,
                             const float* __restrict__ gamma, const float* __restrict__ beta,
                             const float* __restrict__ mean, const float* __restrict__ var,
                             unsigned short* __restrict__ out, int N) {
    __shared__ unsigned short abuf[16][136];
    __shared__ unsigned short hbuf[16][136];
    __shared__ float sx[16], sy[16];
    int tid = threadIdx.x;
    int row0 = blockIdx.x * 16;
    if (row0 >= N) return;
    int lane = tid & 63;

    // ---- phase A: agg2, 16 lanes per row ----
    {
        int lr = tid >> 4, t16 = tid & 15;
        int n = row0 + lr; if (n > N - 1) n = N - 1;
        const float2* x2 = (const float2*)x;
        float ax = 0.f, ay = 0.f;
        int e0 = rowptr[n], e1 = rowptr[n + 1];
        for (int j = e0 + t16; j < e1; j += 16) {
            float2 v = x2[col[j]];
            ax += v.x; ay += v.y;
        }
        ax += __shfl_xor(ax, 1); ay += __shfl_xor(ay, 1);
        ax += __shfl_xor(ax, 2); ay += __shfl_xor(ay, 2);
        ax += __shfl_xor(ax, 4); ay += __shfl_xor(ay, 4);
        ax += __shfl_xor(ax, 8); ay += __shfl_xor(ay, 8);
        if (t16 == 0) {
            float2 self = x2[n];
            sx[lr] = ax + self.x;
            sy[lr] = ay + self.y;
        }
    }
    __syncthreads();

    // ---- phase B: h1 = relu(sum2 @ W1 + b1), permuted positions -> abuf ----
    {
        int lr = tid >> 4;
        int p0 = (tid & 15) * 8;
        float vx = sx[lr], vy = sy[lr];
        float v[8];
#pragma unroll
        for (int k = 0; k < 8; ++k) {
            int pp = p0 + k;
            int c = (pp & 7) * 16 + (pp >> 3);
            v[k] = fmaxf(fmaf(vx, W1[c], fmaf(vy, W1[128 + c], b1[c])), 0.f);
        }
        *(uint4*)&abuf[lr][p0] = pack8bf(v);
    }
    __syncthreads();

    // ---- phase C: GEMM (W2) + BN -> hbuf (permuted positions) ----
    int wv = tid >> 6;
    int m = lane & 15, q = lane >> 4;
    short8 a0[4];
#pragma unroll
    for (int ks = 0; ks < 4; ++ks)
        a0[ks] = *(const short8*)&abuf[m][ks * 32 + q * 8];
    floatx4 c0[2];
    c0[0] = (floatx4){0.f, 0.f, 0.f, 0.f};
    c0[1] = (floatx4){0.f, 0.f, 0.f, 0.f};
#pragma unroll
    for (int nt2 = 0; nt2 < 2; ++nt2) {
        int ntg = (wv << 1) | nt2;
#pragma unroll
        for (int ks = 0; ks < 4; ++ks) {
            short8 w = *(const short8*)&W2p[(((ks << 3) + ntg) * 64 + lane) * 8];
            c0[nt2] = __builtin_amdgcn_mfma_f32_16x16x32_bf16(a0[ks], w, c0[nt2], 0, 0, 0);
        }
    }
    {
        float bv[2], scl[2], shf[2];
#pragma unroll
        for (int nt2 = 0; nt2 < 2; ++nt2) {
            int cidx = ((wv << 1) | nt2) * 16 + m;
            bv[nt2] = b2[cidx];
            float s = gamma[cidx] * rsqrtf(var[cidx] + 1e-5f);
            scl[nt2] = s;
            shf[nt2] = beta[cidx] - mean[cidx] * s;
        }
        int pp = m * 8 + (wv << 1);
#pragma unroll
        for (int rg = 0; rg < 4; ++rg) {
            unsigned u0 = f2bf(fmaf(fmaxf(c0[0][rg] + bv[0], 0.f), scl[0], shf[0]))
                        | (f2bf(fmaf(fmaxf(c0[1][rg] + bv[1], 0.f), scl[1], shf[1])) << 16);
            *(unsigned*)&hbuf[q * 4 + rg][pp] = u0;
        }
    }
    __syncthreads();

    // ---- phase D: coalesced writeout ----
    {
        int lr = tid >> 4;
        int cb = (tid & 15) * 8;
        int n = row0 + lr;
        if (n < N) *(uint4*)&out[(size_t)n * 128 + cb] = *(const uint4*)&hbuf[lr][cb];
    }
}

// ======================= head ==============================================

__global__ void head(const float* __restrict__ pooled,
                     const float* __restrict__ lin1W, const float* __restrict__ lin1b,
                     const float* __restrict__ lin2W, const float* __restrict__ lin2b,
                     float* __restrict__ out) {
    int g = blockIdx.x;
    int c = threadIdx.x;  // 0..127
    __shared__ float pl[128];
    pl[c] = pooled[(size_t)g * 128 + c];
    __syncthreads();

    float o = lin1b[c];
    for (int k = 0; k < 128; ++k) {
        int ko = (k & 7) * 16 + (k >> 3);   // orig col held at permuted position k
        o = fmaf(pl[k], lin1W[ko * 128 + c], o);
    }
    o = fmaxf(o, 0.f) * lin2W[c];

    __shared__ float red[128];
    red[c] = o;
    __syncthreads();
    for (int off = 64; off > 0; off >>= 1) {
        if (c < off) red[c] += red[c + off];
        __syncthreads();
    }
    if (c == 0) out[g] = red[0] + lin2b[0];
}

// ---------------------------------------------------------------------------

extern "C" void kernel_launch(void* const* d_in, const int* in_sizes, int n_in,
                              void* d_out, int out_size, void* d_ws, size_t ws_size,
                              hipStream_t stream) {
    const float* x     = (const float*)d_in[0];
    const int*   ei    = (const int*)d_in[1];
    const int*   batch = (const int*)d_in[2];
    const float* c1W1  = (const float*)d_in[3];
    const float* c1b1  = (const float*)d_in[4];
    const float* c1W2  = (const float*)d_in[5];
    const float* c1b2  = (const float*)d_in[6];
    const float* c1g   = (const float*)d_in[7];
    const float* c1be  = (const float*)d_in[8];
    const float* c1m   = (const float*)d_in[9];
    const float* c1v   = (const float*)d_in[10];
    const float* csW1  = (const float*)d_in[11];
    const float* csb1  = (const float*)d_in[12];
    const float* csW2  = (const float*)d_in[13];
    const float* csb2  = (const float*)d_in[14];
    const float* csg   = (const float*)d_in[15];
    const float* csbe  = (const float*)d_in[16];
    const float* csm   = (const float*)d_in[17];
    const float* csv   = (const float*)d_in[18];
    const float* lin1W = (const float*)d_in[19];
    const float* lin1b = (const float*)d_in[20];
    const float* lin2W = (const float*)d_in[21];
    const float* lin2b = (const float*)d_in[22];

    const int N = in_sizes[0] / 2;
    const int E = in_sizes[1] / 2;
    const int G = out_size;
    const int NL = in_sizes[11] / (128 * 128);  // 4
    const int nb = (N + 127) >> 7;              // buckets of 128 nodes

    char* ws = (char*)d_ws;
    size_t HS = (size_t)N * 128 * sizeof(unsigned short);      // bf16 feature plane
    unsigned short* h   = (unsigned short*)(ws);
    unsigned short* tmp = (unsigned short*)(ws + HS);
    char* p = ws + 2 * HS;
    unsigned short* Wp = (unsigned short*)p; p += ((9 * 16384 * 2 + 15) / 16) * 16;
    int* rowptr = (int*)p;                   p += (((size_t)(N + 1) * 4 + 15) / 16) * 16;
    int* col = (int*)p;                      p += (((size_t)E * 4 + 15) / 16) * 16;
    unsigned* staging = (unsigned*)p;        p += (((size_t)E * 4 + 15) / 16) * 16;
    int* bcnt = (int*)p;                     p += 512 * 4;
    int* boff = (int*)p;                     p += 513 * 4;
    int* bcur = (int*)p;                     p += 512 * 4;
    float* pooled = (float*)p;               p += (size_t)G * 128 * 4;

    const int* srcI = ei;
    const int* dstI = ei + E;

    const int ET = (E + 4095) / 4096;

    // CSR build (bucketed, no scattered global writes)
    (void)hipMemsetAsync(bcnt, 0, 512 * 4, stream);
    (void)hipMemsetAsync(pooled, 0, (size_t)G * 128 * 4, stream);
    bucket_hist<<<ET, 256, 0, stream>>>(dstI, bcnt, E, nb);
    scan_buckets<<<1, 512, 0, stream>>>(bcnt, boff, bcur, rowptr, nb, N);
    bucket_scatter<<<ET, 256, 0, stream>>>(srcI, dstI, bcur, staging, E, nb);
    bucket_build<<<nb, 256, 0, stream>>>(staging, boff, rowptr, col, N);

    // weight packing
    pack_W_all<<<(1 + 2 * NL) * 64, 256, 0, stream>>>(c1W2, csW1, csW2, Wp, NL);

    const int GEMMB = (N + 15) / 16;     // 16 rows per block

    // layer 1 (input dim 2) fully fused
    layer1_fused<<<GEMMB, 256, 0, stream>>>(x, rowptr, col, c1W1, c1b1,
                                            Wp, c1b2, c1g, c1be, c1m, c1v, h, N);

    // layers 2..5 fused (agg + MLP); last layer pools from LDS
    unsigned short* cur = h;
    unsigned short* nxt = tmp;
    for (int i = 0; i < NL; ++i) {
        int last = (i == NL - 1);
        gin_fused<<<GEMMB, 512, 0, stream>>>((const uint4*)cur, rowptr, col,
                                             Wp + (size_t)(1 + i) * 16384, csb1 + i * 128,
                                             Wp + (size_t)(1 + NL + i) * 16384, csb2 + i * 128,
                                             csg + i * 128, csbe + i * 128, csm + i * 128,
                                             csv + i * 128,
                                             nxt, batch, pooled, N, last);
        unsigned short* t = cur; cur = nxt; nxt = t;
    }

    // head
    head<<<G, 128, 0, stream>>>(pooled, lin1W, lin1b, lin2W, lin2b, (float*)d_out);
}

// Round 7
// 372.545 us; speedup vs baseline: 1.1613x; 1.1613x over previous
//
#include <hip/hip_runtime.h>

// ---------------------------------------------------------------------------
// GIN inference, round 17 (= round 16 with the VGPR squeeze fixed):
//  - Round 16's regression was __launch_bounds__(512,8): it forced VGPR=32,
//    the 8-deep gather pipeline spilled to scratch (WRITE_SIZE 1MB->86MB,
//    FETCH +40MB, 72us/layer). Now __launch_bounds__(512,4): VGPR cap 128,
//    natural allocation ~56-64 -> 8 waves/EU without spill.
//  - Gather: 32 lanes/row (2 edge-halves x 16 chunk-lanes) -> ONE 8-deep
//    latency round per row; halves combined via __shfl_xor(acc,16) in-wave.
//  - Rest as round 14: fused agg+GEMM1+GEMM2+(writeout|pool), permuted
//    column layout (position p <-> column (p&7)*16 + (p>>3)).
// ---------------------------------------------------------------------------

typedef __attribute__((ext_vector_type(8))) short short8;   // 8 bf16 (4 VGPRs)
typedef __attribute__((ext_vector_type(4))) float floatx4;  // 4 fp32 acc

__device__ __forceinline__ unsigned f2bf(float f) {
    unsigned u = __float_as_uint(f);
    return (u + 0x7fffu + ((u >> 16) & 1u)) >> 16;   // RNE
}
__device__ __forceinline__ float bf2f(unsigned short b) {
    return __uint_as_float(((unsigned)b) << 16);
}
__device__ __forceinline__ float bflo(unsigned u) { return __uint_as_float(u << 16); }
__device__ __forceinline__ float bfhi(unsigned u) { return __uint_as_float(u & 0xffff0000u); }

__device__ __forceinline__ uint4 pack8bf(const float* v) {
    uint4 o;
    o.x = f2bf(v[0]) | (f2bf(v[1]) << 16);
    o.y = f2bf(v[2]) | (f2bf(v[3]) << 16);
    o.z = f2bf(v[4]) | (f2bf(v[5]) << 16);
    o.w = f2bf(v[6]) | (f2bf(v[7]) << 16);
    return o;
}

// ======================= bucketed CSR build =======================

__global__ void bucket_hist(const int* __restrict__ dstA, int* __restrict__ bcnt,
                            int E, int nb) {
    __shared__ int hist[512];
    int tid = threadIdx.x;
    int start = blockIdx.x * 4096;
    for (int i = tid; i < 512; i += 256) hist[i] = 0;
    __syncthreads();
#pragma unroll
    for (int t = 0; t < 16; ++t) {
        int e = start + t * 256 + tid;
        if (e < E) atomicAdd(&hist[dstA[e] >> 7], 1);
    }
    __syncthreads();
    for (int i = tid; i < nb; i += 256)
        if (hist[i]) atomicAdd(&bcnt[i], hist[i]);
}

__global__ void scan_buckets(const int* __restrict__ bcnt, int* __restrict__ boff,
                             int* __restrict__ bcur, int* __restrict__ rowptr,
                             int nb, int N) {
    __shared__ int sa[512], sb[512];
    int t = threadIdx.x;
    sa[t] = (t < nb) ? bcnt[t] : 0;
    __syncthreads();
    int* ps = sa;
    int* pd = sb;
    for (int o = 1; o < 512; o <<= 1) {
        pd[t] = ps[t] + ((t >= o) ? ps[t - o] : 0);
        __syncthreads();
        int* tmp = ps; ps = pd; pd = tmp;
    }
    if (t <= nb) boff[t] = (t == 0) ? 0 : ps[t - 1];
    if (t < nb) bcur[t] = (t == 0) ? 0 : ps[t - 1];
    if (t == 0) rowptr[N] = ps[nb - 1];
}

__global__ void bucket_scatter(const int* __restrict__ srcA, const int* __restrict__ dstA,
                               int* __restrict__ bcur, unsigned* __restrict__ staging,
                               int E, int nb) {
    __shared__ int hist[512];
    __shared__ int sa[512], sb[512];
    __shared__ int toff[513];
    __shared__ int gbase[512];
    __shared__ unsigned pk[4096];
    __shared__ unsigned short bkt[4096];
    int tid = threadIdx.x;
    int start = blockIdx.x * 4096;
    for (int i = tid; i < 512; i += 256) hist[i] = 0;
    __syncthreads();
    int bidx[16], rank[16];
    unsigned pval[16];
#pragma unroll
    for (int t = 0; t < 16; ++t) {
        int e = start + t * 256 + tid;
        bidx[t] = -1;
        if (e < E) {
            int d = dstA[e];
            int s = srcA[e];
            int b = d >> 7;
            bidx[t] = b;
            rank[t] = atomicAdd(&hist[b], 1);
            pval[t] = ((unsigned)s << 7) | (unsigned)(d & 127);
        }
    }
    __syncthreads();
    sa[tid] = hist[tid];
    sa[tid + 256] = hist[tid + 256];
    __syncthreads();
    int* ps = sa;
    int* pd = sb;
    for (int o = 1; o < 512; o <<= 1) {
        pd[tid] = ps[tid] + ((tid >= o) ? ps[tid - o] : 0);
        int j2 = tid + 256;
        pd[j2] = ps[j2] + ((j2 >= o) ? ps[j2 - o] : 0);
        __syncthreads();
        int* tmp = ps; ps = pd; pd = tmp;
    }
    toff[tid + 1] = ps[tid];
    toff[tid + 257] = ps[tid + 256];
    if (tid == 0) toff[0] = 0;
    __syncthreads();
    for (int b = tid; b < nb; b += 256) {
        int c = hist[b];
        gbase[b] = c ? atomicAdd(&bcur[b], c) : 0;
    }
#pragma unroll
    for (int t = 0; t < 16; ++t)
        if (bidx[t] >= 0) {
            int pos = toff[bidx[t]] + rank[t];
            pk[pos] = pval[t];
            bkt[pos] = (unsigned short)bidx[t];
        }
    __syncthreads();
    int total = toff[512];
    for (int i = tid; i < total; i += 256) {
        int b = bkt[i];
        staging[gbase[b] + (i - toff[b])] = pk[i];
    }
}

__global__ void bucket_build(const unsigned* __restrict__ staging, const int* __restrict__ boff,
                             int* __restrict__ rowptr, int* __restrict__ col, int N) {
    __shared__ int deg[128], sca[128], scb[128], curL[128];
    __shared__ unsigned pk[4096];
    __shared__ int colL[4096];
    int b = blockIdx.x, tid = threadIdx.x;
    int lo = boff[b], hi = boff[b + 1];
    int cnt = hi - lo;
    if (cnt > 4096) cnt = 4096;
    for (int i = tid; i < cnt; i += 256) pk[i] = staging[lo + i];
    if (tid < 128) deg[tid] = 0;
    __syncthreads();
    for (int i = tid; i < cnt; i += 256) atomicAdd(&deg[pk[i] & 127u], 1);
    __syncthreads();
    if (tid < 128) sca[tid] = deg[tid];
    __syncthreads();
    int* ps = sca;
    int* pd = scb;
    for (int o = 1; o < 128; o <<= 1) {
        if (tid < 128) pd[tid] = ps[tid] + ((tid >= o) ? ps[tid - o] : 0);
        __syncthreads();
        int* tmp = ps; ps = pd; pd = tmp;
    }
    if (tid < 128) {
        int excl = tid ? ps[tid - 1] : 0;
        curL[tid] = excl;
        int node = b * 128 + tid;
        if (node < N) rowptr[node] = lo + excl;
    }
    __syncthreads();
    for (int i = tid; i < cnt; i += 256) {
        unsigned v = pk[i];
        int p = atomicAdd(&curL[v & 127u], 1);
        colL[p] = (int)(v >> 7);
    }
    __syncthreads();
    for (int i = tid; i < cnt; i += 256) col[lo + i] = colL[i];
}

// ======================= weight packing (perm-aware) =======================

__global__ void pack_W_all(const float* __restrict__ c1W2, const float* __restrict__ csW1,
                           const float* __restrict__ csW2, unsigned short* __restrict__ Wp,
                           int NL) {
    int slot = blockIdx.x >> 6;
    int r = (blockIdx.x & 63) * 256 + threadIdx.x;   // 0..16383
    const float* W = (slot == 0) ? c1W2
                   : (slot <= NL ? csW1 + (size_t)(slot - 1) * 16384
                                 : csW2 + (size_t)(slot - 1 - NL) * 16384);
    int j = r & 7, lane = (r >> 3) & 63, nt = (r >> 9) & 7, ks = (r >> 12) & 3;
    int u = ks * 32 + (lane >> 4) * 8 + j;
    int k = (u & 7) * 16 + (u >> 3);                 // pi(u)
    int n = nt * 16 + (lane & 15);
    Wp[(size_t)slot * 16384 + r] = (unsigned short)f2bf(W[k * 128 + n]);
}

// ======================= helpers =======================

__device__ __forceinline__ void addrow(float* acc, uint4 v) {
    acc[0] += bflo(v.x); acc[1] += bfhi(v.x);
    acc[2] += bflo(v.y); acc[3] += bfhi(v.y);
    acc[4] += bflo(v.z); acc[5] += bfhi(v.z);
    acc[6] += bflo(v.w); acc[7] += bfhi(v.w);
}

// ======================= fused GIN layer (agg + MLP + out/pool) ============
// 512 threads / block, 16 rows / block. Phase A: 32 lanes per row (2 edge
// halves x 16 chunk-lanes); halves combined via __shfl_xor(.,16) in-wave.
// Phases B/C: 8 waves, one nt-tile each. Permuted column layout:
// position p <-> actual column (p&7)*16 + (p>>3).

__launch_bounds__(512, 4)
__global__ void gin_fused(const uint4* __restrict__ h4,
                          const int* __restrict__ rowptr, const int* __restrict__ col,
                          const unsigned short* __restrict__ W1p, const float* __restrict__ b1,
                          const unsigned short* __restrict__ W2p, const float* __restrict__ b2,
                          const float* __restrict__ gamma, const float* __restrict__ beta,
                          const float* __restrict__ mean, const float* __restrict__ var,
                          unsigned short* __restrict__ out,
                          const int* __restrict__ batch, float* __restrict__ pooled,
                          int N, int last) {
    __shared__ unsigned short abuf[16][136];   // agg output, reused for BN output
    __shared__ unsigned short hbuf[16][136];   // GEMM1 -> GEMM2 handoff
    int tid = threadIdx.x;
    int row0 = blockIdx.x * 16;
    if (row0 >= N) return;
    int lane = tid & 63;
    int wv = tid >> 6;                         // 0..7

    // ---- phase A: gather; 32 lanes/row = 2 edge-halves x 16 chunks ----
    {
        int slot = tid >> 5;                   // row in block, 0..15
        int hh = (tid >> 4) & 1;               // edge half
        int sl = tid & 15;                     // 16B chunk of the 256B row
        int n = row0 + slot;
        if (n > N - 1) n = N - 1;              // tail: duplicate row N-1 (discarded)
        float acc[8];
        if (hh == 0) {
            uint4 self = h4[(size_t)n * 16 + sl];
            acc[0] = bflo(self.x); acc[1] = bfhi(self.x);
            acc[2] = bflo(self.y); acc[3] = bfhi(self.y);
            acc[4] = bflo(self.z); acc[5] = bfhi(self.z);
            acc[6] = bflo(self.w); acc[7] = bfhi(self.w);
        } else {
#pragma unroll
            for (int t = 0; t < 8; ++t) acc[t] = 0.f;
        }
        int e0 = rowptr[n], e1 = rowptr[n + 1];
        int half = (e1 - e0 + 1) >> 1;
        int ja = hh ? e0 + half : e0;
        int jb = hh ? e1 : e0 + half;
        int j = ja;
        for (; j + 8 <= jb; j += 8) {
            int s[8];
#pragma unroll
            for (int t = 0; t < 8; ++t) s[t] = col[j + t];
            uint4 v[8];
#pragma unroll
            for (int t = 0; t < 8; ++t) v[t] = h4[(size_t)s[t] * 16 + sl];
#pragma unroll
            for (int t = 0; t < 8; ++t) addrow(acc, v[t]);
        }
        for (; j + 4 <= jb; j += 4) {
            int s0 = col[j], s1 = col[j + 1], s2 = col[j + 2], s3 = col[j + 3];
            uint4 v0 = h4[(size_t)s0 * 16 + sl];
            uint4 v1 = h4[(size_t)s1 * 16 + sl];
            uint4 v2 = h4[(size_t)s2 * 16 + sl];
            uint4 v3 = h4[(size_t)s3 * 16 + sl];
            addrow(acc, v0); addrow(acc, v1); addrow(acc, v2); addrow(acc, v3);
        }
        for (; j < jb; ++j) addrow(acc, h4[(size_t)col[j] * 16 + sl]);
        // combine halves in-wave: partner is lane^16 (same wave, same row)
#pragma unroll
        for (int t = 0; t < 8; ++t) acc[t] += __shfl_xor(acc[t], 16);
        if (hh == 0) *(uint4*)&abuf[slot][sl * 8] = pack8bf(acc);
    }
    __syncthreads();

    // ---- phase B: GEMM1 (wave owns nt-tile ntg = wv) ----
    int m = lane & 15, q = lane >> 4;
    short8 a0[4];
#pragma unroll
    for (int ks = 0; ks < 4; ++ks)
        a0[ks] = *(const short8*)&abuf[m][ks * 32 + q * 8];
    floatx4 c0 = (floatx4){0.f, 0.f, 0.f, 0.f};
#pragma unroll
    for (int ks = 0; ks < 4; ++ks) {
        short8 w = *(const short8*)&W1p[(((ks << 3) + wv) * 64 + lane) * 8];
        c0 = __builtin_amdgcn_mfma_f32_16x16x32_bf16(a0[ks], w, c0, 0, 0, 0);
    }
    {
        // column wv*16+m -> permuted position m*8+wv
        float bv0 = b1[wv * 16 + m];
        int pp = m * 8 + wv;
#pragma unroll
        for (int rg = 0; rg < 4; ++rg)
            hbuf[q * 4 + rg][pp] = (unsigned short)f2bf(fmaxf(c0[rg] + bv0, 0.f));
    }
    __syncthreads();

    // ---- phase C: GEMM2 + BN epilogue -> abuf (reuse) ----
    short8 d0[4];
#pragma unroll
    for (int ks = 0; ks < 4; ++ks)
        d0[ks] = *(const short8*)&hbuf[m][ks * 32 + q * 8];
    floatx4 e0v = (floatx4){0.f, 0.f, 0.f, 0.f};
#pragma unroll
    for (int ks = 0; ks < 4; ++ks) {
        short8 w = *(const short8*)&W2p[(((ks << 3) + wv) * 64 + lane) * 8];
        e0v = __builtin_amdgcn_mfma_f32_16x16x32_bf16(d0[ks], w, e0v, 0, 0, 0);
    }
    {
        int cidx = wv * 16 + m;
        float bv = b2[cidx];
        float s = gamma[cidx] * rsqrtf(var[cidx] + 1e-5f);
        float sh = beta[cidx] - mean[cidx] * s;
        int pp = m * 8 + wv;
#pragma unroll
        for (int rg = 0; rg < 4; ++rg)
            abuf[q * 4 + rg][pp] =
                (unsigned short)f2bf(fmaf(fmaxf(e0v[rg] + bv, 0.f), s, sh));
    }
    __syncthreads();

    // ---- phase D: coalesced writeout (non-last) or pool-from-LDS (last) ----
    if (!last) {
        int lr = tid >> 5;
        int cb = (tid & 31) * 4;
        int n = row0 + lr;
        if (n < N) *(uint2*)&out[(size_t)n * 128 + cb] = *(const uint2*)&abuf[lr][cb];
    } else if (tid < 128) {
        int n1 = N - row0; if (n1 > 16) n1 = 16;
        int cg = batch[row0];
        float acc = 0.f;
        for (int lr = 0; lr < n1; ++lr) {
            int g = batch[row0 + lr];
            if (g != cg) {
                atomicAdd(&pooled[(size_t)cg * 128 + tid], acc);
                acc = 0.f;
                cg = g;
            }
            acc += bf2f(abuf[lr][tid]);
        }
        atomicAdd(&pooled[(size_t)cg * 128 + tid], acc);
    }
}

// ======================= fused layer 1 (agg2 + W1-MLP + W2 GEMM) ===========

__launch_bounds__(256)
__global__ void layer1_fused(const float* __restrict__ x,
                             const int* __restrict__ rowptr, const int* __restrict__ col,
                             const float* __restrict__ W1, const float* __restrict__ b1,
                             const unsigned short* __restrict__ W2p, const float* __restrict__ b2,
                             const float* __restrict__ gamma, const float* __restrict__ beta,
                             const float* __restrict__ mean, const float* __restrict__ var,
                             unsigned short* __restrict__ out, int N) {
    __shared__ unsigned short abuf[16][136];
    __shared__ unsigned short hbuf[16][136];
    __shared__ float sx[16], sy[16];
    int tid = threadIdx.x;
    int row0 = blockIdx.x * 16;
    if (row0 >= N) return;
    int lane = tid & 63;

    // ---- phase A: agg2, 16 lanes per row ----
    {
        int lr = tid >> 4, t16 = tid & 15;
        int n = row0 + lr; if (n > N - 1) n = N - 1;
        const float2* x2 = (const float2*)x;
        float ax = 0.f, ay = 0.f;
        int e0 = rowptr[n], e1 = rowptr[n + 1];
        for (int j = e0 + t16; j < e1; j += 16) {
            float2 v = x2[col[j]];
            ax += v.x; ay += v.y;
        }
        ax += __shfl_xor(ax, 1); ay += __shfl_xor(ay, 1);
        ax += __shfl_xor(ax, 2); ay += __shfl_xor(ay, 2);
        ax += __shfl_xor(ax, 4); ay += __shfl_xor(ay, 4);
        ax += __shfl_xor(ax, 8); ay += __shfl_xor(ay, 8);
        if (t16 == 0) {
            float2 self = x2[n];
            sx[lr] = ax + self.x;
            sy[lr] = ay + self.y;
        }
    }
    __syncthreads();

    // ---- phase B: h1 = relu(sum2 @ W1 + b1), permuted positions -> abuf ----
    {
        int lr = tid >> 4;
        int p0 = (tid & 15) * 8;
        float vx = sx[lr], vy = sy[lr];
        float v[8];
#pragma unroll
        for (int k = 0; k < 8; ++k) {
            int pp = p0 + k;
            int c = (pp & 7) * 16 + (pp >> 3);
            v[k] = fmaxf(fmaf(vx, W1[c], fmaf(vy, W1[128 + c], b1[c])), 0.f);
        }
        *(uint4*)&abuf[lr][p0] = pack8bf(v);
    }
    __syncthreads();

    // ---- phase C: GEMM (W2) + BN -> hbuf (permuted positions) ----
    int wv = tid >> 6;
    int m = lane & 15, q = lane >> 4;
    short8 a0[4];
#pragma unroll
    for (int ks = 0; ks < 4; ++ks)
        a0[ks] = *(const short8*)&abuf[m][ks * 32 + q * 8];
    floatx4 c0[2];
    c0[0] = (floatx4){0.f, 0.f, 0.f, 0.f};
    c0[1] = (floatx4){0.f, 0.f, 0.f, 0.f};
#pragma unroll
    for (int nt2 = 0; nt2 < 2; ++nt2) {
        int ntg = (wv << 1) | nt2;
#pragma unroll
        for (int ks = 0; ks < 4; ++ks) {
            short8 w = *(const short8*)&W2p[(((ks << 3) + ntg) * 64 + lane) * 8];
            c0[nt2] = __builtin_amdgcn_mfma_f32_16x16x32_bf16(a0[ks], w, c0[nt2], 0, 0, 0);
        }
    }
    {
        float bv[2], scl[2], shf[2];
#pragma unroll
        for (int nt2 = 0; nt2 < 2; ++nt2) {
            int cidx = ((wv << 1) | nt2) * 16 + m;
            bv[nt2] = b2[cidx];
            float s = gamma[cidx] * rsqrtf(var[cidx] + 1e-5f);
            scl[nt2] = s;
            shf[nt2] = beta[cidx] - mean[cidx] * s;
        }
        int pp = m * 8 + (wv << 1);
#pragma unroll
        for (int rg = 0; rg < 4; ++rg) {
            unsigned u0 = f2bf(fmaf(fmaxf(c0[0][rg] + bv[0], 0.f), scl[0], shf[0]))
                        | (f2bf(fmaf(fmaxf(c0[1][rg] + bv[1], 0.f), scl[1], shf[1])) << 16);
            *(unsigned*)&hbuf[q * 4 + rg][pp] = u0;
        }
    }
    __syncthreads();

    // ---- phase D: coalesced writeout ----
    {
        int lr = tid >> 4;
        int cb = (tid & 15) * 8;
        int n = row0 + lr;
        if (n < N) *(uint4*)&out[(size_t)n * 128 + cb] = *(const uint4*)&hbuf[lr][cb];
    }
}

// ======================= head ==============================================

__global__ void head(const float* __restrict__ pooled,
                     const float* __restrict__ lin1W, const float* __restrict__ lin1b,
                     const float* __restrict__ lin2W, const float* __restrict__ lin2b,
                     float* __restrict__ out) {
    int g = blockIdx.x;
    int c = threadIdx.x;  // 0..127
    __shared__ float pl[128];
    pl[c] = pooled[(size_t)g * 128 + c];
    __syncthreads();

    float o = lin1b[c];
    for (int k = 0; k < 128; ++k) {
        int ko = (k & 7) * 16 + (k >> 3);   // orig col held at permuted position k
        o = fmaf(pl[k], lin1W[ko * 128 + c], o);
    }
    o = fmaxf(o, 0.f) * lin2W[c];

    __shared__ float red[128];
    red[c] = o;
    __syncthreads();
    for (int off = 64; off > 0; off >>= 1) {
        if (c < off) red[c] += red[c + off];
        __syncthreads();
    }
    if (c == 0) out[g] = red[0] + lin2b[0];
}

// ---------------------------------------------------------------------------

extern "C" void kernel_launch(void* const* d_in, const int* in_sizes, int n_in,
                              void* d_out, int out_size, void* d_ws, size_t ws_size,
                              hipStream_t stream) {
    const float* x     = (const float*)d_in[0];
    const int*   ei    = (const int*)d_in[1];
    const int*   batch = (const int*)d_in[2];
    const float* c1W1  = (const float*)d_in[3];
    const float* c1b1  = (const float*)d_in[4];
    const float* c1W2  = (const float*)d_in[5];
    const float* c1b2  = (const float*)d_in[6];
    const float* c1g   = (const float*)d_in[7];
    const float* c1be  = (const float*)d_in[8];
    const float* c1m   = (const float*)d_in[9];
    const float* c1v   = (const float*)d_in[10];
    const float* csW1  = (const float*)d_in[11];
    const float* csb1  = (const float*)d_in[12];
    const float* csW2  = (const float*)d_in[13];
    const float* csb2  = (const float*)d_in[14];
    const float* csg   = (const float*)d_in[15];
    const float* csbe  = (const float*)d_in[16];
    const float* csm   = (const float*)d_in[17];
    const float* csv   = (const float*)d_in[18];
    const float* lin1W = (const float*)d_in[19];
    const float* lin1b = (const float*)d_in[20];
    const float* lin2W = (const float*)d_in[21];
    const float* lin2b = (const float*)d_in[22];

    const int N = in_sizes[0] / 2;
    const int E = in_sizes[1] / 2;
    const int G = out_size;
    const int NL = in_sizes[11] / (128 * 128);  // 4
    const int nb = (N + 127) >> 7;              // buckets of 128 nodes

    char* ws = (char*)d_ws;
    size_t HS = (size_t)N * 128 * sizeof(unsigned short);      // bf16 feature plane
    unsigned short* h   = (unsigned short*)(ws);
    unsigned short* tmp = (unsigned short*)(ws + HS);
    char* p = ws + 2 * HS;
    unsigned short* Wp = (unsigned short*)p; p += ((9 * 16384 * 2 + 15) / 16) * 16;
    int* rowptr = (int*)p;                   p += (((size_t)(N + 1) * 4 + 15) / 16) * 16;
    int* col = (int*)p;                      p += (((size_t)E * 4 + 15) / 16) * 16;
    unsigned* staging = (unsigned*)p;        p += (((size_t)E * 4 + 15) / 16) * 16;
    int* bcnt = (int*)p;                     p += 512 * 4;
    int* boff = (int*)p;                     p += 513 * 4;
    int* bcur = (int*)p;                     p += 512 * 4;
    float* pooled = (float*)p;               p += (size_t)G * 128 * 4;

    const int* srcI = ei;
    const int* dstI = ei + E;

    const int ET = (E + 4095) / 4096;

    // CSR build (bucketed, no scattered global writes)
    (void)hipMemsetAsync(bcnt, 0, 512 * 4, stream);
    (void)hipMemsetAsync(pooled, 0, (size_t)G * 128 * 4, stream);
    bucket_hist<<<ET, 256, 0, stream>>>(dstI, bcnt, E, nb);
    scan_buckets<<<1, 512, 0, stream>>>(bcnt, boff, bcur, rowptr, nb, N);
    bucket_scatter<<<ET, 256, 0, stream>>>(srcI, dstI, bcur, staging, E, nb);
    bucket_build<<<nb, 256, 0, stream>>>(staging, boff, rowptr, col, N);

    // weight packing
    pack_W_all<<<(1 + 2 * NL) * 64, 256, 0, stream>>>(c1W2, csW1, csW2, Wp, NL);

    const int GEMMB = (N + 15) / 16;     // 16 rows per block

    // layer 1 (input dim 2) fully fused
    layer1_fused<<<GEMMB, 256, 0, stream>>>(x, rowptr, col, c1W1, c1b1,
                                            Wp, c1b2, c1g, c1be, c1m, c1v, h, N);

    // layers 2..5 fused (agg + MLP); last layer pools from LDS
    unsigned short* cur = h;
    unsigned short* nxt = tmp;
    for (int i = 0; i < NL; ++i) {
        int last = (i == NL - 1);
        gin_fused<<<GEMMB, 512, 0, stream>>>((const uint4*)cur, rowptr, col,
                                             Wp + (size_t)(1 + i) * 16384, csb1 + i * 128,
                                             Wp + (size_t)(1 + NL + i) * 16384, csb2 + i * 128,
                                             csg + i * 128, csbe + i * 128, csm + i * 128,
                                             csv + i * 128,
                                             nxt, batch, pooled, N, last);
        unsigned short* t = cur; cur = nxt; nxt = t;
    }

    // head
    head<<<G, 128, 0, stream>>>(pooled, lin1W, lin1b, lin2W, lin2b, (float*)d_out);
}

// Round 8
// 332.852 us; speedup vs baseline: 1.2997x; 1.1193x over previous
//
#include <hip/hip_runtime.h>

// ---------------------------------------------------------------------------
// GIN inference, round 18 (= round 14 structure + streaming-load hints):
//  - Round 14 (16 rows / 256-thread block, one 16-lane slot per row, 8-deep
//    gather) is the verified best (313.5us). Rounds 13/15/16/17 disproved
//    traffic-, issue-, and chain-length theories; the gather sits at the
//    memory system's random-row service rate for this structure.
//  - This round: __builtin_nontemporal_load on the single-use streams (col,
//    batch) so they don't evict feature-plane lines from per-XCD L2. Plane
//    loads remain cacheable.
// ---------------------------------------------------------------------------

typedef __attribute__((ext_vector_type(8))) short short8;   // 8 bf16 (4 VGPRs)
typedef __attribute__((ext_vector_type(4))) float floatx4;  // 4 fp32 acc

__device__ __forceinline__ unsigned f2bf(float f) {
    unsigned u = __float_as_uint(f);
    return (u + 0x7fffu + ((u >> 16) & 1u)) >> 16;   // RNE
}
__device__ __forceinline__ float bf2f(unsigned short b) {
    return __uint_as_float(((unsigned)b) << 16);
}
__device__ __forceinline__ float bflo(unsigned u) { return __uint_as_float(u << 16); }
__device__ __forceinline__ float bfhi(unsigned u) { return __uint_as_float(u & 0xffff0000u); }

__device__ __forceinline__ uint4 pack8bf(const float* v) {
    uint4 o;
    o.x = f2bf(v[0]) | (f2bf(v[1]) << 16);
    o.y = f2bf(v[2]) | (f2bf(v[3]) << 16);
    o.z = f2bf(v[4]) | (f2bf(v[5]) << 16);
    o.w = f2bf(v[6]) | (f2bf(v[7]) << 16);
    return o;
}

// ======================= bucketed CSR build =======================

__global__ void bucket_hist(const int* __restrict__ dstA, int* __restrict__ bcnt,
                            int E, int nb) {
    __shared__ int hist[512];
    int tid = threadIdx.x;
    int start = blockIdx.x * 4096;
    for (int i = tid; i < 512; i += 256) hist[i] = 0;
    __syncthreads();
#pragma unroll
    for (int t = 0; t < 16; ++t) {
        int e = start + t * 256 + tid;
        if (e < E) atomicAdd(&hist[dstA[e] >> 7], 1);
    }
    __syncthreads();
    for (int i = tid; i < nb; i += 256)
        if (hist[i]) atomicAdd(&bcnt[i], hist[i]);
}

__global__ void scan_buckets(const int* __restrict__ bcnt, int* __restrict__ boff,
                             int* __restrict__ bcur, int* __restrict__ rowptr,
                             int nb, int N) {
    __shared__ int sa[512], sb[512];
    int t = threadIdx.x;
    sa[t] = (t < nb) ? bcnt[t] : 0;
    __syncthreads();
    int* ps = sa;
    int* pd = sb;
    for (int o = 1; o < 512; o <<= 1) {
        pd[t] = ps[t] + ((t >= o) ? ps[t - o] : 0);
        __syncthreads();
        int* tmp = ps; ps = pd; pd = tmp;
    }
    if (t <= nb) boff[t] = (t == 0) ? 0 : ps[t - 1];
    if (t < nb) bcur[t] = (t == 0) ? 0 : ps[t - 1];
    if (t == 0) rowptr[N] = ps[nb - 1];
}

__global__ void bucket_scatter(const int* __restrict__ srcA, const int* __restrict__ dstA,
                               int* __restrict__ bcur, unsigned* __restrict__ staging,
                               int E, int nb) {
    __shared__ int hist[512];
    __shared__ int sa[512], sb[512];
    __shared__ int toff[513];
    __shared__ int gbase[512];
    __shared__ unsigned pk[4096];
    __shared__ unsigned short bkt[4096];
    int tid = threadIdx.x;
    int start = blockIdx.x * 4096;
    for (int i = tid; i < 512; i += 256) hist[i] = 0;
    __syncthreads();
    int bidx[16], rank[16];
    unsigned pval[16];
#pragma unroll
    for (int t = 0; t < 16; ++t) {
        int e = start + t * 256 + tid;
        bidx[t] = -1;
        if (e < E) {
            int d = dstA[e];
            int s = srcA[e];
            int b = d >> 7;
            bidx[t] = b;
            rank[t] = atomicAdd(&hist[b], 1);
            pval[t] = ((unsigned)s << 7) | (unsigned)(d & 127);
        }
    }
    __syncthreads();
    sa[tid] = hist[tid];
    sa[tid + 256] = hist[tid + 256];
    __syncthreads();
    int* ps = sa;
    int* pd = sb;
    for (int o = 1; o < 512; o <<= 1) {
        pd[tid] = ps[tid] + ((tid >= o) ? ps[tid - o] : 0);
        int j2 = tid + 256;
        pd[j2] = ps[j2] + ((j2 >= o) ? ps[j2 - o] : 0);
        __syncthreads();
        int* tmp = ps; ps = pd; pd = tmp;
    }
    toff[tid + 1] = ps[tid];
    toff[tid + 257] = ps[tid + 256];
    if (tid == 0) toff[0] = 0;
    __syncthreads();
    for (int b = tid; b < nb; b += 256) {
        int c = hist[b];
        gbase[b] = c ? atomicAdd(&bcur[b], c) : 0;
    }
#pragma unroll
    for (int t = 0; t < 16; ++t)
        if (bidx[t] >= 0) {
            int pos = toff[bidx[t]] + rank[t];
            pk[pos] = pval[t];
            bkt[pos] = (unsigned short)bidx[t];
        }
    __syncthreads();
    int total = toff[512];
    for (int i = tid; i < total; i += 256) {
        int b = bkt[i];
        staging[gbase[b] + (i - toff[b])] = pk[i];
    }
}

__global__ void bucket_build(const unsigned* __restrict__ staging, const int* __restrict__ boff,
                             int* __restrict__ rowptr, int* __restrict__ col, int N) {
    __shared__ int deg[128], sca[128], scb[128], curL[128];
    __shared__ unsigned pk[4096];
    __shared__ int colL[4096];
    int b = blockIdx.x, tid = threadIdx.x;
    int lo = boff[b], hi = boff[b + 1];
    int cnt = hi - lo;
    if (cnt > 4096) cnt = 4096;
    for (int i = tid; i < cnt; i += 256) pk[i] = staging[lo + i];
    if (tid < 128) deg[tid] = 0;
    __syncthreads();
    for (int i = tid; i < cnt; i += 256) atomicAdd(&deg[pk[i] & 127u], 1);
    __syncthreads();
    if (tid < 128) sca[tid] = deg[tid];
    __syncthreads();
    int* ps = sca;
    int* pd = scb;
    for (int o = 1; o < 128; o <<= 1) {
        if (tid < 128) pd[tid] = ps[tid] + ((tid >= o) ? ps[tid - o] : 0);
        __syncthreads();
        int* tmp = ps; ps = pd; pd = tmp;
    }
    if (tid < 128) {
        int excl = tid ? ps[tid - 1] : 0;
        curL[tid] = excl;
        int node = b * 128 + tid;
        if (node < N) rowptr[node] = lo + excl;
    }
    __syncthreads();
    for (int i = tid; i < cnt; i += 256) {
        unsigned v = pk[i];
        int p = atomicAdd(&curL[v & 127u], 1);
        colL[p] = (int)(v >> 7);
    }
    __syncthreads();
    for (int i = tid; i < cnt; i += 256) col[lo + i] = colL[i];
}

// ======================= weight packing (perm-aware) =======================

__global__ void pack_W_all(const float* __restrict__ c1W2, const float* __restrict__ csW1,
                           const float* __restrict__ csW2, unsigned short* __restrict__ Wp,
                           int NL) {
    int slot = blockIdx.x >> 6;
    int r = (blockIdx.x & 63) * 256 + threadIdx.x;   // 0..16383
    const float* W = (slot == 0) ? c1W2
                   : (slot <= NL ? csW1 + (size_t)(slot - 1) * 16384
                                 : csW2 + (size_t)(slot - 1 - NL) * 16384);
    int j = r & 7, lane = (r >> 3) & 63, nt = (r >> 9) & 7, ks = (r >> 12) & 3;
    int u = ks * 32 + (lane >> 4) * 8 + j;
    int k = (u & 7) * 16 + (u >> 3);                 // pi(u)
    int n = nt * 16 + (lane & 15);
    Wp[(size_t)slot * 16384 + r] = (unsigned short)f2bf(W[k * 128 + n]);
}

// ======================= helpers =======================

__device__ __forceinline__ void addrow(float* acc, uint4 v) {
    acc[0] += bflo(v.x); acc[1] += bfhi(v.x);
    acc[2] += bflo(v.y); acc[3] += bfhi(v.y);
    acc[4] += bflo(v.z); acc[5] += bfhi(v.z);
    acc[6] += bflo(v.w); acc[7] += bfhi(v.w);
}

// ======================= fused GIN layer (agg + MLP + out/pool) ============
// 256 threads / block, 16 rows / block. Phase A: one 16-lane slot per row,
// 8-deep gather, col via non-temporal loads (single-use stream; keeps L2
// for the feature plane). Phases B/C: 4 waves split the 8 nt-tiles.
// Permuted column layout: position p <-> column (p&7)*16 + (p>>3).

__launch_bounds__(256)
__global__ void gin_fused(const uint4* __restrict__ h4,
                          const int* __restrict__ rowptr, const int* __restrict__ col,
                          const unsigned short* __restrict__ W1p, const float* __restrict__ b1,
                          const unsigned short* __restrict__ W2p, const float* __restrict__ b2,
                          const float* __restrict__ gamma, const float* __restrict__ beta,
                          const float* __restrict__ mean, const float* __restrict__ var,
                          unsigned short* __restrict__ out,
                          const int* __restrict__ batch, float* __restrict__ pooled,
                          int N, int last) {
    __shared__ unsigned short abuf[16][136];   // agg output, reused for BN output
    __shared__ unsigned short hbuf[16][136];   // GEMM1 -> GEMM2 handoff
    int tid = threadIdx.x;
    int row0 = blockIdx.x * 16;
    if (row0 >= N) return;
    int lane = tid & 63;
    int wv = tid >> 6;

    // ---- phase A: gather 16 rows, one 16-lane slot each, single pass ----
    {
        int slot = tid >> 4;         // row in block, 0..15
        int sl = tid & 15;           // 16B sub-chunk of the 256B row
        int n = row0 + slot;
        if (n > N - 1) n = N - 1;    // tail: duplicate row N-1 (discarded)
        size_t base = (size_t)n * 16 + sl;
        uint4 self = h4[base];
        float acc[8];
        acc[0] = bflo(self.x); acc[1] = bfhi(self.x);
        acc[2] = bflo(self.y); acc[3] = bfhi(self.y);
        acc[4] = bflo(self.z); acc[5] = bfhi(self.z);
        acc[6] = bflo(self.w); acc[7] = bfhi(self.w);
        int e0 = rowptr[n], e1 = rowptr[n + 1];
        int j = e0;
        for (; j + 8 <= e1; j += 8) {
            int s[8];
#pragma unroll
            for (int t = 0; t < 8; ++t) s[t] = __builtin_nontemporal_load(&col[j + t]);
            uint4 v[8];
#pragma unroll
            for (int t = 0; t < 8; ++t) v[t] = h4[(size_t)s[t] * 16 + sl];
#pragma unroll
            for (int t = 0; t < 8; ++t) addrow(acc, v[t]);
        }
        for (; j + 4 <= e1; j += 4) {
            int s0 = __builtin_nontemporal_load(&col[j]);
            int s1 = __builtin_nontemporal_load(&col[j + 1]);
            int s2 = __builtin_nontemporal_load(&col[j + 2]);
            int s3 = __builtin_nontemporal_load(&col[j + 3]);
            uint4 v0 = h4[(size_t)s0 * 16 + sl];
            uint4 v1 = h4[(size_t)s1 * 16 + sl];
            uint4 v2 = h4[(size_t)s2 * 16 + sl];
            uint4 v3 = h4[(size_t)s3 * 16 + sl];
            addrow(acc, v0); addrow(acc, v1); addrow(acc, v2); addrow(acc, v3);
        }
        for (; j < e1; ++j)
            addrow(acc, h4[(size_t)__builtin_nontemporal_load(&col[j]) * 16 + sl]);
        *(uint4*)&abuf[slot][sl * 8] = pack8bf(acc);
    }
    __syncthreads();

    // ---- phase B: GEMM1 (wave owns nt = 2wv, 2wv+1) ----
    int m = lane & 15, q = lane >> 4;
    short8 a0[4];
#pragma unroll
    for (int ks = 0; ks < 4; ++ks)
        a0[ks] = *(const short8*)&abuf[m][ks * 32 + q * 8];
    floatx4 c0[2];
    c0[0] = (floatx4){0.f, 0.f, 0.f, 0.f};
    c0[1] = (floatx4){0.f, 0.f, 0.f, 0.f};
#pragma unroll
    for (int nt2 = 0; nt2 < 2; ++nt2) {
        int ntg = (wv << 1) | nt2;
#pragma unroll
        for (int ks = 0; ks < 4; ++ks) {
            short8 w = *(const short8*)&W1p[(((ks << 3) + ntg) * 64 + lane) * 8];
            c0[nt2] = __builtin_amdgcn_mfma_f32_16x16x32_bf16(a0[ks], w, c0[nt2], 0, 0, 0);
        }
    }
    {
        // column ntg*16+m -> permuted position m*8+ntg; wave's two ntg are
        // adjacent positions -> one aligned u32 store per row.
        float bv0 = b1[((wv << 1) | 0) * 16 + m];
        float bv1 = b1[((wv << 1) | 1) * 16 + m];
        int pp = m * 8 + (wv << 1);
#pragma unroll
        for (int rg = 0; rg < 4; ++rg) {
            unsigned u0 = f2bf(fmaxf(c0[0][rg] + bv0, 0.f))
                        | (f2bf(fmaxf(c0[1][rg] + bv1, 0.f)) << 16);
            *(unsigned*)&hbuf[q * 4 + rg][pp] = u0;
        }
    }
    __syncthreads();

    // ---- phase C: GEMM2 + BN epilogue -> abuf (reuse) ----
    short8 d0[4];
#pragma unroll
    for (int ks = 0; ks < 4; ++ks)
        d0[ks] = *(const short8*)&hbuf[m][ks * 32 + q * 8];
    floatx4 e0v[2];
    e0v[0] = (floatx4){0.f, 0.f, 0.f, 0.f};
    e0v[1] = (floatx4){0.f, 0.f, 0.f, 0.f};
#pragma unroll
    for (int nt2 = 0; nt2 < 2; ++nt2) {
        int ntg = (wv << 1) | nt2;
#pragma unroll
        for (int ks = 0; ks < 4; ++ks) {
            short8 w = *(const short8*)&W2p[(((ks << 3) + ntg) * 64 + lane) * 8];
            e0v[nt2] = __builtin_amdgcn_mfma_f32_16x16x32_bf16(d0[ks], w, e0v[nt2], 0, 0, 0);
        }
    }
    {
        float bv[2], scl[2], shf[2];
#pragma unroll
        for (int nt2 = 0; nt2 < 2; ++nt2) {
            int cidx = ((wv << 1) | nt2) * 16 + m;
            bv[nt2] = b2[cidx];
            float s = gamma[cidx] * rsqrtf(var[cidx] + 1e-5f);
            scl[nt2] = s;
            shf[nt2] = beta[cidx] - mean[cidx] * s;
        }
        int pp = m * 8 + (wv << 1);
#pragma unroll
        for (int rg = 0; rg < 4; ++rg) {
            unsigned u0 = f2bf(fmaf(fmaxf(e0v[0][rg] + bv[0], 0.f), scl[0], shf[0]))
                        | (f2bf(fmaf(fmaxf(e0v[1][rg] + bv[1], 0.f), scl[1], shf[1])) << 16);
            *(unsigned*)&abuf[q * 4 + rg][pp] = u0;
        }
    }
    __syncthreads();

    // ---- phase D: coalesced writeout (non-last) or pool-from-LDS (last) ----
    if (!last) {
        int lr = tid >> 4;
        int cb = (tid & 15) * 8;
        int n = row0 + lr;
        if (n < N) *(uint4*)&out[(size_t)n * 128 + cb] = *(const uint4*)&abuf[lr][cb];
    } else if (tid < 128) {
        int n1 = N - row0; if (n1 > 16) n1 = 16;
        int cg = __builtin_nontemporal_load(&batch[row0]);
        float acc = 0.f;
        for (int lr = 0; lr < n1; ++lr) {
            int g = __builtin_nontemporal_load(&batch[row0 + lr]);
            if (g != cg) {
                atomicAdd(&pooled[(size_t)cg * 128 + tid], acc);
                acc = 0.f;
                cg = g;
            }
            acc += bf2f(abuf[lr][tid]);
        }
        atomicAdd(&pooled[(size_t)cg * 128 + tid], acc);
    }
}

// ======================= fused layer 1 (agg2 + W1-MLP + W2 GEMM) ===========

__launch_bounds__(256)
__global__ void layer1_fused(const float* __restrict__ x,
                             const int* __restrict__ rowptr, const int* __restrict__ col,
                             const float* __restrict__ W1, const float* __restrict__ b1,
                             const unsigned short* __restrict__ W2p, const float* __restrict__ b2,
                             const float* __restrict__ gamma, const float* __restrict__ beta,
                             const float* __restrict__ mean, const float* __restrict__ var,
                             unsigned short* __restrict__ out, int N) {
    __shared__ unsigned short abuf[16][136];
    __shared__ unsigned short hbuf[16][136];
    __shared__ float sx[16], sy[16];
    int tid = threadIdx.x;
    int row0 = blockIdx.x * 16;
    if (row0 >= N) return;
    int lane = tid & 63;

    // ---- phase A: agg2, 16 lanes per row ----
    {
        int lr = tid >> 4, t16 = tid & 15;
        int n = row0 + lr; if (n > N - 1) n = N - 1;
        const float2* x2 = (const float2*)x;
        float ax = 0.f, ay = 0.f;
        int e0 = rowptr[n], e1 = rowptr[n + 1];
        for (int j = e0 + t16; j < e1; j += 16) {
            float2 v = x2[__builtin_nontemporal_load(&col[j])];
            ax += v.x; ay += v.y;
        }
        ax += __shfl_xor(ax, 1); ay += __shfl_xor(ay, 1);
        ax += __shfl_xor(ax, 2); ay += __shfl_xor(ay, 2);
        ax += __shfl_xor(ax, 4); ay += __shfl_xor(ay, 4);
        ax += __shfl_xor(ax, 8); ay += __shfl_xor(ay, 8);
        if (t16 == 0) {
            float2 self = x2[n];
            sx[lr] = ax + self.x;
            sy[lr] = ay + self.y;
        }
    }
    __syncthreads();

    // ---- phase B: h1 = relu(sum2 @ W1 + b1), permuted positions -> abuf ----
    {
        int lr = tid >> 4;
        int p0 = (tid & 15) * 8;
        float vx = sx[lr], vy = sy[lr];
        float v[8];
#pragma unroll
        for (int k = 0; k < 8; ++k) {
            int pp = p0 + k;
            int c = (pp & 7) * 16 + (pp >> 3);
            v[k] = fmaxf(fmaf(vx, W1[c], fmaf(vy, W1[128 + c], b1[c])), 0.f);
        }
        *(uint4*)&abuf[lr][p0] = pack8bf(v);
    }
    __syncthreads();

    // ---- phase C: GEMM (W2) + BN -> hbuf (permuted positions) ----
    int wv = tid >> 6;
    int m = lane & 15, q = lane >> 4;
    short8 a0[4];
#pragma unroll
    for (int ks = 0; ks < 4; ++ks)
        a0[ks] = *(const short8*)&abuf[m][ks * 32 + q * 8];
    floatx4 c0[2];
    c0[0] = (floatx4){0.f, 0.f, 0.f, 0.f};
    c0[1] = (floatx4){0.f, 0.f, 0.f, 0.f};
#pragma unroll
    for (int nt2 = 0; nt2 < 2; ++nt2) {
        int ntg = (wv << 1) | nt2;
#pragma unroll
        for (int ks = 0; ks < 4; ++ks) {
            short8 w = *(const short8*)&W2p[(((ks << 3) + ntg) * 64 + lane) * 8];
            c0[nt2] = __builtin_amdgcn_mfma_f32_16x16x32_bf16(a0[ks], w, c0[nt2], 0, 0, 0);
        }
    }
    {
        float bv[2], scl[2], shf[2];
#pragma unroll
        for (int nt2 = 0; nt2 < 2; ++nt2) {
            int cidx = ((wv << 1) | nt2) * 16 + m;
            bv[nt2] = b2[cidx];
            float s = gamma[cidx] * rsqrtf(var[cidx] + 1e-5f);
            scl[nt2] = s;
            shf[nt2] = beta[cidx] - mean[cidx] * s;
        }
        int pp = m * 8 + (wv << 1);
#pragma unroll
        for (int rg = 0; rg < 4; ++rg) {
            unsigned u0 = f2bf(fmaf(fmaxf(c0[0][rg] + bv[0], 0.f), scl[0], shf[0]))
                        | (f2bf(fmaf(fmaxf(c0[1][rg] + bv[1], 0.f), scl[1], shf[1])) << 16);
            *(unsigned*)&hbuf[q * 4 + rg][pp] = u0;
        }
    }
    __syncthreads();

    // ---- phase D: coalesced writeout ----
    {
        int lr = tid >> 4;
        int cb = (tid & 15) * 8;
        int n = row0 + lr;
        if (n < N) *(uint4*)&out[(size_t)n * 128 + cb] = *(const uint4*)&hbuf[lr][cb];
    }
}

// ======================= head ==============================================

__global__ void head(const float* __restrict__ pooled,
                     const float* __restrict__ lin1W, const float* __restrict__ lin1b,
                     const float* __restrict__ lin2W, const float* __restrict__ lin2b,
                     float* __restrict__ out) {
    int g = blockIdx.x;
    int c = threadIdx.x;  // 0..127
    __shared__ float pl[128];
    pl[c] = pooled[(size_t)g * 128 + c];
    __syncthreads();

    float o = lin1b[c];
    for (int k = 0; k < 128; ++k) {
        int ko = (k & 7) * 16 + (k >> 3);   // orig col held at permuted position k
        o = fmaf(pl[k], lin1W[ko * 128 + c], o);
    }
    o = fmaxf(o, 0.f) * lin2W[c];

    __shared__ float red[128];
    red[c] = o;
    __syncthreads();
    for (int off = 64; off > 0; off >>= 1) {
        if (c < off) red[c] += red[c + off];
        __syncthreads();
    }
    if (c == 0) out[g] = red[0] + lin2b[0];
}

// ---------------------------------------------------------------------------

extern "C" void kernel_launch(void* const* d_in, const int* in_sizes, int n_in,
                              void* d_out, int out_size, void* d_ws, size_t ws_size,
                              hipStream_t stream) {
    const float* x     = (const float*)d_in[0];
    const int*   ei    = (const int*)d_in[1];
    const int*   batch = (const int*)d_in[2];
    const float* c1W1  = (const float*)d_in[3];
    const float* c1b1  = (const float*)d_in[4];
    const float* c1W2  = (const float*)d_in[5];
    const float* c1b2  = (const float*)d_in[6];
    const float* c1g   = (const float*)d_in[7];
    const float* c1be  = (const float*)d_in[8];
    const float* c1m   = (const float*)d_in[9];
    const float* c1v   = (const float*)d_in[10];
    const float* csW1  = (const float*)d_in[11];
    const float* csb1  = (const float*)d_in[12];
    const float* csW2  = (const float*)d_in[13];
    const float* csb2  = (const float*)d_in[14];
    const float* csg   = (const float*)d_in[15];
    const float* csbe  = (const float*)d_in[16];
    const float* csm   = (const float*)d_in[17];
    const float* csv   = (const float*)d_in[18];
    const float* lin1W = (const float*)d_in[19];
    const float* lin1b = (const float*)d_in[20];
    const float* lin2W = (const float*)d_in[21];
    const float* lin2b = (const float*)d_in[22];

    const int N = in_sizes[0] / 2;
    const int E = in_sizes[1] / 2;
    const int G = out_size;
    const int NL = in_sizes[11] / (128 * 128);  // 4
    const int nb = (N + 127) >> 7;              // buckets of 128 nodes

    char* ws = (char*)d_ws;
    size_t HS = (size_t)N * 128 * sizeof(unsigned short);      // bf16 feature plane
    unsigned short* h   = (unsigned short*)(ws);
    unsigned short* tmp = (unsigned short*)(ws + HS);
    char* p = ws + 2 * HS;
    unsigned short* Wp = (unsigned short*)p; p += ((9 * 16384 * 2 + 15) / 16) * 16;
    int* rowptr = (int*)p;                   p += (((size_t)(N + 1) * 4 + 15) / 16) * 16;
    int* col = (int*)p;                      p += (((size_t)E * 4 + 15) / 16) * 16;
    unsigned* staging = (unsigned*)p;        p += (((size_t)E * 4 + 15) / 16) * 16;
    int* bcnt = (int*)p;                     p += 512 * 4;
    int* boff = (int*)p;                     p += 513 * 4;
    int* bcur = (int*)p;                     p += 512 * 4;
    float* pooled = (float*)p;               p += (size_t)G * 128 * 4;

    const int* srcI = ei;
    const int* dstI = ei + E;

    const int ET = (E + 4095) / 4096;

    // CSR build (bucketed, no scattered global writes)
    (void)hipMemsetAsync(bcnt, 0, 512 * 4, stream);
    (void)hipMemsetAsync(pooled, 0, (size_t)G * 128 * 4, stream);
    bucket_hist<<<ET, 256, 0, stream>>>(dstI, bcnt, E, nb);
    scan_buckets<<<1, 512, 0, stream>>>(bcnt, boff, bcur, rowptr, nb, N);
    bucket_scatter<<<ET, 256, 0, stream>>>(srcI, dstI, bcur, staging, E, nb);
    bucket_build<<<nb, 256, 0, stream>>>(staging, boff, rowptr, col, N);

    // weight packing
    pack_W_all<<<(1 + 2 * NL) * 64, 256, 0, stream>>>(c1W2, csW1, csW2, Wp, NL);

    const int GEMMB = (N + 15) / 16;     // 16 rows per 256-thread block

    // layer 1 (input dim 2) fully fused
    layer1_fused<<<GEMMB, 256, 0, stream>>>(x, rowptr, col, c1W1, c1b1,
                                            Wp, c1b2, c1g, c1be, c1m, c1v, h, N);

    // layers 2..5 fused (agg + MLP); last layer pools from LDS
    unsigned short* cur = h;
    unsigned short* nxt = tmp;
    for (int i = 0; i < NL; ++i) {
        int last = (i == NL - 1);
        gin_fused<<<GEMMB, 256, 0, stream>>>((const uint4*)cur, rowptr, col,
                                             Wp + (size_t)(1 + i) * 16384, csb1 + i * 128,
                                             Wp + (size_t)(1 + NL + i) * 16384, csb2 + i * 128,
                                             csg + i * 128, csbe + i * 128, csm + i * 128,
                                             csv + i * 128,
                                             nxt, batch, pooled, N, last);
        unsigned short* t = cur; cur = nxt; nxt = t;
    }

    // head
    head<<<G, 128, 0, stream>>>(pooled, lin1W, lin1b, lin2W, lin2b, (float*)d_out);
}

// Round 9
// 305.302 us; speedup vs baseline: 1.4170x; 1.0902x over previous
//
#include <hip/hip_runtime.h>

// ---------------------------------------------------------------------------
// GIN inference, round 19 (= round 14 best structure + CSR-build trim):
//  - Round 18's nontemporal col loads REVERTED (+6%: col is 16-way
//    redundantly read within a row-slot; nt bypassed the near caches that
//    served 15/16 of those reads).
//  - CSR build: bucket_hist kernel DELETED. staging is now fixed-capacity
//    [nb][4096] bucket regions; bucket_scatter reserves space with one
//    atomicAdd(&bcnt[b], c) per non-empty bucket per block (expected fill
//    2048 +- 45, cap 4096 = 45 sigma). scan prefixes final counts -> boff
//    for compacted col. Saves one 3.2MB read pass + one dispatch.
//  - Gather ledger closed (R13 traffic, R14 occupancy, R15 issue-count,
//    R16/17 chain-length, R18 cache policy): phase A sits at the memory
//    system's random-64B-line service rate (~5 TB/s effective).
// ---------------------------------------------------------------------------

typedef __attribute__((ext_vector_type(8))) short short8;   // 8 bf16 (4 VGPRs)
typedef __attribute__((ext_vector_type(4))) float floatx4;  // 4 fp32 acc

__device__ __forceinline__ unsigned f2bf(float f) {
    unsigned u = __float_as_uint(f);
    return (u + 0x7fffu + ((u >> 16) & 1u)) >> 16;   // RNE
}
__device__ __forceinline__ float bf2f(unsigned short b) {
    return __uint_as_float(((unsigned)b) << 16);
}
__device__ __forceinline__ float bflo(unsigned u) { return __uint_as_float(u << 16); }
__device__ __forceinline__ float bfhi(unsigned u) { return __uint_as_float(u & 0xffff0000u); }

__device__ __forceinline__ uint4 pack8bf(const float* v) {
    uint4 o;
    o.x = f2bf(v[0]) | (f2bf(v[1]) << 16);
    o.y = f2bf(v[2]) | (f2bf(v[3]) << 16);
    o.z = f2bf(v[4]) | (f2bf(v[5]) << 16);
    o.w = f2bf(v[6]) | (f2bf(v[7]) << 16);
    return o;
}

// ======================= bucketed CSR build (2 kernels + scan) =============

// scatter with direct atomic reservation into fixed-capacity bucket regions
__global__ void bucket_scatter(const int* __restrict__ srcA, const int* __restrict__ dstA,
                               int* __restrict__ bcnt, unsigned* __restrict__ staging,
                               int E, int nb) {
    __shared__ int hist[512];
    __shared__ int sa[512], sb[512];
    __shared__ int toff[513];
    __shared__ int gbase[512];
    __shared__ unsigned pk[4096];
    __shared__ unsigned short bkt[4096];
    int tid = threadIdx.x;
    int start = blockIdx.x * 4096;
    for (int i = tid; i < 512; i += 256) hist[i] = 0;
    __syncthreads();
    int bidx[16], rank[16];
    unsigned pval[16];
#pragma unroll
    for (int t = 0; t < 16; ++t) {
        int e = start + t * 256 + tid;
        bidx[t] = -1;
        if (e < E) {
            int d = dstA[e];
            int s = srcA[e];
            int b = d >> 7;
            bidx[t] = b;
            rank[t] = atomicAdd(&hist[b], 1);
            pval[t] = ((unsigned)s << 7) | (unsigned)(d & 127);
        }
    }
    __syncthreads();
    sa[tid] = hist[tid];
    sa[tid + 256] = hist[tid + 256];
    __syncthreads();
    int* ps = sa;
    int* pd = sb;
    for (int o = 1; o < 512; o <<= 1) {
        pd[tid] = ps[tid] + ((tid >= o) ? ps[tid - o] : 0);
        int j2 = tid + 256;
        pd[j2] = ps[j2] + ((j2 >= o) ? ps[j2 - o] : 0);
        __syncthreads();
        int* tmp = ps; ps = pd; pd = tmp;
    }
    toff[tid + 1] = ps[tid];
    toff[tid + 257] = ps[tid + 256];
    if (tid == 0) toff[0] = 0;
    __syncthreads();
    // reserve space in each touched bucket's fixed region
    for (int b = tid; b < nb; b += 256) {
        int c = hist[b];
        gbase[b] = c ? atomicAdd(&bcnt[b], c) : 0;
    }
#pragma unroll
    for (int t = 0; t < 16; ++t)
        if (bidx[t] >= 0) {
            int pos = toff[bidx[t]] + rank[t];
            pk[pos] = pval[t];
            bkt[pos] = (unsigned short)bidx[t];
        }
    __syncthreads();
    int total = toff[512];
    for (int i = tid; i < total; i += 256) {
        int b = bkt[i];
        int pos = gbase[b] + (i - toff[b]);
        if (pos < 4096)
            staging[(size_t)b * 4096 + pos] = pk[i];
    }
}

__global__ void scan_buckets(const int* __restrict__ bcnt, int* __restrict__ boff,
                             int* __restrict__ rowptr, int nb, int N) {
    __shared__ int sa[512], sb[512];
    int t = threadIdx.x;
    int c = (t < nb) ? bcnt[t] : 0;
    sa[t] = (c > 4096) ? 4096 : c;
    __syncthreads();
    int* ps = sa;
    int* pd = sb;
    for (int o = 1; o < 512; o <<= 1) {
        pd[t] = ps[t] + ((t >= o) ? ps[t - o] : 0);
        __syncthreads();
        int* tmp = ps; ps = pd; pd = tmp;
    }
    if (t <= nb) boff[t] = (t == 0) ? 0 : ps[t - 1];
    if (t == 0) rowptr[N] = ps[nb - 1];
}

__global__ void bucket_build(const unsigned* __restrict__ staging, const int* __restrict__ boff,
                             const int* __restrict__ bcntA,
                             int* __restrict__ rowptr, int* __restrict__ col, int N) {
    __shared__ int deg[128], sca[128], scb[128], curL[128];
    __shared__ unsigned pk[4096];
    __shared__ int colL[4096];
    int b = blockIdx.x, tid = threadIdx.x;
    int lo = boff[b];
    int cnt = bcntA[b];
    if (cnt > 4096) cnt = 4096;
    for (int i = tid; i < cnt; i += 256) pk[i] = staging[(size_t)b * 4096 + i];
    if (tid < 128) deg[tid] = 0;
    __syncthreads();
    for (int i = tid; i < cnt; i += 256) atomicAdd(&deg[pk[i] & 127u], 1);
    __syncthreads();
    if (tid < 128) sca[tid] = deg[tid];
    __syncthreads();
    int* ps = sca;
    int* pd = scb;
    for (int o = 1; o < 128; o <<= 1) {
        if (tid < 128) pd[tid] = ps[tid] + ((tid >= o) ? ps[tid - o] : 0);
        __syncthreads();
        int* tmp = ps; ps = pd; pd = tmp;
    }
    if (tid < 128) {
        int excl = tid ? ps[tid - 1] : 0;
        curL[tid] = excl;
        int node = b * 128 + tid;
        if (node < N) rowptr[node] = lo + excl;
    }
    __syncthreads();
    for (int i = tid; i < cnt; i += 256) {
        unsigned v = pk[i];
        int p = atomicAdd(&curL[v & 127u], 1);
        colL[p] = (int)(v >> 7);
    }
    __syncthreads();
    for (int i = tid; i < cnt; i += 256) col[lo + i] = colL[i];
}

// ======================= weight packing (perm-aware) =======================

__global__ void pack_W_all(const float* __restrict__ c1W2, const float* __restrict__ csW1,
                           const float* __restrict__ csW2, unsigned short* __restrict__ Wp,
                           int NL) {
    int slot = blockIdx.x >> 6;
    int r = (blockIdx.x & 63) * 256 + threadIdx.x;   // 0..16383
    const float* W = (slot == 0) ? c1W2
                   : (slot <= NL ? csW1 + (size_t)(slot - 1) * 16384
                                 : csW2 + (size_t)(slot - 1 - NL) * 16384);
    int j = r & 7, lane = (r >> 3) & 63, nt = (r >> 9) & 7, ks = (r >> 12) & 3;
    int u = ks * 32 + (lane >> 4) * 8 + j;
    int k = (u & 7) * 16 + (u >> 3);                 // pi(u)
    int n = nt * 16 + (lane & 15);
    Wp[(size_t)slot * 16384 + r] = (unsigned short)f2bf(W[k * 128 + n]);
}

// ======================= helpers =======================

__device__ __forceinline__ void addrow(float* acc, uint4 v) {
    acc[0] += bflo(v.x); acc[1] += bfhi(v.x);
    acc[2] += bflo(v.y); acc[3] += bfhi(v.y);
    acc[4] += bflo(v.z); acc[5] += bfhi(v.z);
    acc[6] += bflo(v.w); acc[7] += bfhi(v.w);
}

// ======================= fused GIN layer (agg + MLP + out/pool) ============
// 256 threads / block, 16 rows / block (round-14 verified best). Phase A:
// one 16-lane slot per row, 8-deep gather. Phases B/C: 4 waves split the
// 8 nt-tiles. Permuted column layout: position p <-> column (p&7)*16+(p>>3).

__launch_bounds__(256)
__global__ void gin_fused(const uint4* __restrict__ h4,
                          const int* __restrict__ rowptr, const int* __restrict__ col,
                          const unsigned short* __restrict__ W1p, const float* __restrict__ b1,
                          const unsigned short* __restrict__ W2p, const float* __restrict__ b2,
                          const float* __restrict__ gamma, const float* __restrict__ beta,
                          const float* __restrict__ mean, const float* __restrict__ var,
                          unsigned short* __restrict__ out,
                          const int* __restrict__ batch, float* __restrict__ pooled,
                          int N, int last) {
    __shared__ unsigned short abuf[16][136];   // agg output, reused for BN output
    __shared__ unsigned short hbuf[16][136];   // GEMM1 -> GEMM2 handoff
    int tid = threadIdx.x;
    int row0 = blockIdx.x * 16;
    if (row0 >= N) return;
    int lane = tid & 63;
    int wv = tid >> 6;

    // ---- phase A: gather 16 rows, one 16-lane slot each, single pass ----
    {
        int slot = tid >> 4;         // row in block, 0..15
        int sl = tid & 15;           // 16B sub-chunk of the 256B row
        int n = row0 + slot;
        if (n > N - 1) n = N - 1;    // tail: duplicate row N-1 (discarded)
        size_t base = (size_t)n * 16 + sl;
        uint4 self = h4[base];
        float acc[8];
        acc[0] = bflo(self.x); acc[1] = bfhi(self.x);
        acc[2] = bflo(self.y); acc[3] = bfhi(self.y);
        acc[4] = bflo(self.z); acc[5] = bfhi(self.z);
        acc[6] = bflo(self.w); acc[7] = bfhi(self.w);
        int e0 = rowptr[n], e1 = rowptr[n + 1];
        int j = e0;
        for (; j + 8 <= e1; j += 8) {
            int s[8];
#pragma unroll
            for (int t = 0; t < 8; ++t) s[t] = col[j + t];
            uint4 v[8];
#pragma unroll
            for (int t = 0; t < 8; ++t) v[t] = h4[(size_t)s[t] * 16 + sl];
#pragma unroll
            for (int t = 0; t < 8; ++t) addrow(acc, v[t]);
        }
        for (; j + 4 <= e1; j += 4) {
            int s0 = col[j], s1 = col[j + 1], s2 = col[j + 2], s3 = col[j + 3];
            uint4 v0 = h4[(size_t)s0 * 16 + sl];
            uint4 v1 = h4[(size_t)s1 * 16 + sl];
            uint4 v2 = h4[(size_t)s2 * 16 + sl];
            uint4 v3 = h4[(size_t)s3 * 16 + sl];
            addrow(acc, v0); addrow(acc, v1); addrow(acc, v2); addrow(acc, v3);
        }
        for (; j < e1; ++j) addrow(acc, h4[(size_t)col[j] * 16 + sl]);
        *(uint4*)&abuf[slot][sl * 8] = pack8bf(acc);
    }
    __syncthreads();

    // ---- phase B: GEMM1 (wave owns nt = 2wv, 2wv+1) ----
    int m = lane & 15, q = lane >> 4;
    short8 a0[4];
#pragma unroll
    for (int ks = 0; ks < 4; ++ks)
        a0[ks] = *(const short8*)&abuf[m][ks * 32 + q * 8];
    floatx4 c0[2];
    c0[0] = (floatx4){0.f, 0.f, 0.f, 0.f};
    c0[1] = (floatx4){0.f, 0.f, 0.f, 0.f};
#pragma unroll
    for (int nt2 = 0; nt2 < 2; ++nt2) {
        int ntg = (wv << 1) | nt2;
#pragma unroll
        for (int ks = 0; ks < 4; ++ks) {
            short8 w = *(const short8*)&W1p[(((ks << 3) + ntg) * 64 + lane) * 8];
            c0[nt2] = __builtin_amdgcn_mfma_f32_16x16x32_bf16(a0[ks], w, c0[nt2], 0, 0, 0);
        }
    }
    {
        // column ntg*16+m -> permuted position m*8+ntg; wave's two ntg are
        // adjacent positions -> one aligned u32 store per row.
        float bv0 = b1[((wv << 1) | 0) * 16 + m];
        float bv1 = b1[((wv << 1) | 1) * 16 + m];
        int pp = m * 8 + (wv << 1);
#pragma unroll
        for (int rg = 0; rg < 4; ++rg) {
            unsigned u0 = f2bf(fmaxf(c0[0][rg] + bv0, 0.f))
                        | (f2bf(fmaxf(c0[1][rg] + bv1, 0.f)) << 16);
            *(unsigned*)&hbuf[q * 4 + rg][pp] = u0;
        }
    }
    __syncthreads();

    // ---- phase C: GEMM2 + BN epilogue -> abuf (reuse) ----
    short8 d0[4];
#pragma unroll
    for (int ks = 0; ks < 4; ++ks)
        d0[ks] = *(const short8*)&hbuf[m][ks * 32 + q * 8];
    floatx4 e0v[2];
    e0v[0] = (floatx4){0.f, 0.f, 0.f, 0.f};
    e0v[1] = (floatx4){0.f, 0.f, 0.f, 0.f};
#pragma unroll
    for (int nt2 = 0; nt2 < 2; ++nt2) {
        int ntg = (wv << 1) | nt2;
#pragma unroll
        for (int ks = 0; ks < 4; ++ks) {
            short8 w = *(const short8*)&W2p[(((ks << 3) + ntg) * 64 + lane) * 8];
            e0v[nt2] = __builtin_amdgcn_mfma_f32_16x16x32_bf16(d0[ks], w, e0v[nt2], 0, 0, 0);
        }
    }
    {
        float bv[2], scl[2], shf[2];
#pragma unroll
        for (int nt2 = 0; nt2 < 2; ++nt2) {
            int cidx = ((wv << 1) | nt2) * 16 + m;
            bv[nt2] = b2[cidx];
            float s = gamma[cidx] * rsqrtf(var[cidx] + 1e-5f);
            scl[nt2] = s;
            shf[nt2] = beta[cidx] - mean[cidx] * s;
        }
        int pp = m * 8 + (wv << 1);
#pragma unroll
        for (int rg = 0; rg < 4; ++rg) {
            unsigned u0 = f2bf(fmaf(fmaxf(e0v[0][rg] + bv[0], 0.f), scl[0], shf[0]))
                        | (f2bf(fmaf(fmaxf(e0v[1][rg] + bv[1], 0.f), scl[1], shf[1])) << 16);
            *(unsigned*)&abuf[q * 4 + rg][pp] = u0;
        }
    }
    __syncthreads();

    // ---- phase D: coalesced writeout (non-last) or pool-from-LDS (last) ----
    if (!last) {
        int lr = tid >> 4;
        int cb = (tid & 15) * 8;
        int n = row0 + lr;
        if (n < N) *(uint4*)&out[(size_t)n * 128 + cb] = *(const uint4*)&abuf[lr][cb];
    } else if (tid < 128) {
        int n1 = N - row0; if (n1 > 16) n1 = 16;
        int cg = batch[row0];
        float acc = 0.f;
        for (int lr = 0; lr < n1; ++lr) {
            int g = batch[row0 + lr];
            if (g != cg) {
                atomicAdd(&pooled[(size_t)cg * 128 + tid], acc);
                acc = 0.f;
                cg = g;
            }
            acc += bf2f(abuf[lr][tid]);
        }
        atomicAdd(&pooled[(size_t)cg * 128 + tid], acc);
    }
}

// ======================= fused layer 1 (agg2 + W1-MLP + W2 GEMM) ===========

__launch_bounds__(256)
__global__ void layer1_fused(const float* __restrict__ x,
                             const int* __restrict__ rowptr, const int* __restrict__ col,
                             const float* __restrict__ W1, const float* __restrict__ b1,
                             const unsigned short* __restrict__ W2p, const float* __restrict__ b2,
                             const float* __restrict__ gamma, const float* __restrict__ beta,
                             const float* __restrict__ mean, const float* __restrict__ var,
                             unsigned short* __restrict__ out, int N) {
    __shared__ unsigned short abuf[16][136];
    __shared__ unsigned short hbuf[16][136];
    __shared__ float sx[16], sy[16];
    int tid = threadIdx.x;
    int row0 = blockIdx.x * 16;
    if (row0 >= N) return;
    int lane = tid & 63;

    // ---- phase A: agg2, 16 lanes per row ----
    {
        int lr = tid >> 4, t16 = tid & 15;
        int n = row0 + lr; if (n > N - 1) n = N - 1;
        const float2* x2 = (const float2*)x;
        float ax = 0.f, ay = 0.f;
        int e0 = rowptr[n], e1 = rowptr[n + 1];
        for (int j = e0 + t16; j < e1; j += 16) {
            float2 v = x2[col[j]];
            ax += v.x; ay += v.y;
        }
        ax += __shfl_xor(ax, 1); ay += __shfl_xor(ay, 1);
        ax += __shfl_xor(ax, 2); ay += __shfl_xor(ay, 2);
        ax += __shfl_xor(ax, 4); ay += __shfl_xor(ay, 4);
        ax += __shfl_xor(ax, 8); ay += __shfl_xor(ay, 8);
        if (t16 == 0) {
            float2 self = x2[n];
            sx[lr] = ax + self.x;
            sy[lr] = ay + self.y;
        }
    }
    __syncthreads();

    // ---- phase B: h1 = relu(sum2 @ W1 + b1), permuted positions -> abuf ----
    {
        int lr = tid >> 4;
        int p0 = (tid & 15) * 8;
        float vx = sx[lr], vy = sy[lr];
        float v[8];
#pragma unroll
        for (int k = 0; k < 8; ++k) {
            int pp = p0 + k;
            int c = (pp & 7) * 16 + (pp >> 3);
            v[k] = fmaxf(fmaf(vx, W1[c], fmaf(vy, W1[128 + c], b1[c])), 0.f);
        }
        *(uint4*)&abuf[lr][p0] = pack8bf(v);
    }
    __syncthreads();

    // ---- phase C: GEMM (W2) + BN -> hbuf (permuted positions) ----
    int wv = tid >> 6;
    int m = lane & 15, q = lane >> 4;
    short8 a0[4];
#pragma unroll
    for (int ks = 0; ks < 4; ++ks)
        a0[ks] = *(const short8*)&abuf[m][ks * 32 + q * 8];
    floatx4 c0[2];
    c0[0] = (floatx4){0.f, 0.f, 0.f, 0.f};
    c0[1] = (floatx4){0.f, 0.f, 0.f, 0.f};
#pragma unroll
    for (int nt2 = 0; nt2 < 2; ++nt2) {
        int ntg = (wv << 1) | nt2;
#pragma unroll
        for (int ks = 0; ks < 4; ++ks) {
            short8 w = *(const short8*)&W2p[(((ks << 3) + ntg) * 64 + lane) * 8];
            c0[nt2] = __builtin_amdgcn_mfma_f32_16x16x32_bf16(a0[ks], w, c0[nt2], 0, 0, 0);
        }
    }
    {
        float bv[2], scl[2], shf[2];
#pragma unroll
        for (int nt2 = 0; nt2 < 2; ++nt2) {
            int cidx = ((wv << 1) | nt2) * 16 + m;
            bv[nt2] = b2[cidx];
            float s = gamma[cidx] * rsqrtf(var[cidx] + 1e-5f);
            scl[nt2] = s;
            shf[nt2] = beta[cidx] - mean[cidx] * s;
        }
        int pp = m * 8 + (wv << 1);
#pragma unroll
        for (int rg = 0; rg < 4; ++rg) {
            unsigned u0 = f2bf(fmaf(fmaxf(c0[0][rg] + bv[0], 0.f), scl[0], shf[0]))
                        | (f2bf(fmaf(fmaxf(c0[1][rg] + bv[1], 0.f), scl[1], shf[1])) << 16);
            *(unsigned*)&hbuf[q * 4 + rg][pp] = u0;
        }
    }
    __syncthreads();

    // ---- phase D: coalesced writeout ----
    {
        int lr = tid >> 4;
        int cb = (tid & 15) * 8;
        int n = row0 + lr;
        if (n < N) *(uint4*)&out[(size_t)n * 128 + cb] = *(const uint4*)&hbuf[lr][cb];
    }
}

// ======================= head ==============================================

__global__ void head(const float* __restrict__ pooled,
                     const float* __restrict__ lin1W, const float* __restrict__ lin1b,
                     const float* __restrict__ lin2W, const float* __restrict__ lin2b,
                     float* __restrict__ out) {
    int g = blockIdx.x;
    int c = threadIdx.x;  // 0..127
    __shared__ float pl[128];
    pl[c] = pooled[(size_t)g * 128 + c];
    __syncthreads();

    float o = lin1b[c];
    for (int k = 0; k < 128; ++k) {
        int ko = (k & 7) * 16 + (k >> 3);   // orig col held at permuted position k
        o = fmaf(pl[k], lin1W[ko * 128 + c], o);
    }
    o = fmaxf(o, 0.f) * lin2W[c];

    __shared__ float red[128];
    red[c] = o;
    __syncthreads();
    for (int off = 64; off > 0; off >>= 1) {
        if (c < off) red[c] += red[c + off];
        __syncthreads();
    }
    if (c == 0) out[g] = red[0] + lin2b[0];
}

// ---------------------------------------------------------------------------

extern "C" void kernel_launch(void* const* d_in, const int* in_sizes, int n_in,
                              void* d_out, int out_size, void* d_ws, size_t ws_size,
                              hipStream_t stream) {
    const float* x     = (const float*)d_in[0];
    const int*   ei    = (const int*)d_in[1];
    const int*   batch = (const int*)d_in[2];
    const float* c1W1  = (const float*)d_in[3];
    const float* c1b1  = (const float*)d_in[4];
    const float* c1W2  = (const float*)d_in[5];
    const float* c1b2  = (const float*)d_in[6];
    const float* c1g   = (const float*)d_in[7];
    const float* c1be  = (const float*)d_in[8];
    const float* c1m   = (const float*)d_in[9];
    const float* c1v   = (const float*)d_in[10];
    const float* csW1  = (const float*)d_in[11];
    const float* csb1  = (const float*)d_in[12];
    const float* csW2  = (const float*)d_in[13];
    const float* csb2  = (const float*)d_in[14];
    const float* csg   = (const float*)d_in[15];
    const float* csbe  = (const float*)d_in[16];
    const float* csm   = (const float*)d_in[17];
    const float* csv   = (const float*)d_in[18];
    const float* lin1W = (const float*)d_in[19];
    const float* lin1b = (const float*)d_in[20];
    const float* lin2W = (const float*)d_in[21];
    const float* lin2b = (const float*)d_in[22];

    const int N = in_sizes[0] / 2;
    const int E = in_sizes[1] / 2;
    const int G = out_size;
    const int NL = in_sizes[11] / (128 * 128);  // 4
    const int nb = (N + 127) >> 7;              // buckets of 128 nodes

    char* ws = (char*)d_ws;
    size_t HS = (size_t)N * 128 * sizeof(unsigned short);      // bf16 feature plane
    unsigned short* h   = (unsigned short*)(ws);
    unsigned short* tmp = (unsigned short*)(ws + HS);
    char* p = ws + 2 * HS;
    unsigned short* Wp = (unsigned short*)p; p += ((9 * 16384 * 2 + 15) / 16) * 16;
    int* rowptr = (int*)p;                   p += (((size_t)(N + 1) * 4 + 15) / 16) * 16;
    int* col = (int*)p;                      p += (((size_t)E * 4 + 15) / 16) * 16;
    unsigned* staging = (unsigned*)p;        p += (size_t)nb * 4096 * 4;   // fixed-capacity buckets
    int* bcnt = (int*)p;                     p += 512 * 4;
    int* boff = (int*)p;                     p += 513 * 4;
    float* pooled = (float*)p;               p += (size_t)G * 128 * 4;

    const int* srcI = ei;
    const int* dstI = ei + E;

    const int ET = (E + 4095) / 4096;

    // CSR build (bucketed, fixed-capacity regions, no hist pass)
    (void)hipMemsetAsync(bcnt, 0, 512 * 4, stream);
    (void)hipMemsetAsync(pooled, 0, (size_t)G * 128 * 4, stream);
    bucket_scatter<<<ET, 256, 0, stream>>>(srcI, dstI, bcnt, staging, E, nb);
    scan_buckets<<<1, 512, 0, stream>>>(bcnt, boff, rowptr, nb, N);
    bucket_build<<<nb, 256, 0, stream>>>(staging, boff, bcnt, rowptr, col, N);

    // weight packing
    pack_W_all<<<(1 + 2 * NL) * 64, 256, 0, stream>>>(c1W2, csW1, csW2, Wp, NL);

    const int GEMMB = (N + 15) / 16;     // 16 rows per 256-thread block

    // layer 1 (input dim 2) fully fused
    layer1_fused<<<GEMMB, 256, 0, stream>>>(x, rowptr, col, c1W1, c1b1,
                                            Wp, c1b2, c1g, c1be, c1m, c1v, h, N);

    // layers 2..5 fused (agg + MLP); last layer pools from LDS
    unsigned short* cur = h;
    unsigned short* nxt = tmp;
    for (int i = 0; i < NL; ++i) {
        int last = (i == NL - 1);
        gin_fused<<<GEMMB, 256, 0, stream>>>((const uint4*)cur, rowptr, col,
                                             Wp + (size_t)(1 + i) * 16384, csb1 + i * 128,
                                             Wp + (size_t)(1 + NL + i) * 16384, csb2 + i * 128,
                                             csg + i * 128, csbe + i * 128, csm + i * 128,
                                             csv + i * 128,
                                             nxt, batch, pooled, N, last);
        unsigned short* t = cur; cur = nxt; nxt = t;
    }

    // head
    head<<<G, 128, 0, stream>>>(pooled, lin1W, lin1b, lin2W, lin2b, (float*)d_out);
}